// Round 8
// baseline (582.950 us; speedup 1.0000x reference)
//
#include <hip/hip_runtime.h>
#include <hip/hip_bf16.h>
#include <stdint.h>

#define EPSV 1e-6f
#define N1 4096
#define N2 4096
#define DD 1024
#define NLAYERS 3
#define KKC 10

typedef __bf16 bf16_t;
typedef __bf16 bf16x8 __attribute__((ext_vector_type(8)));
typedef float f32x4 __attribute__((ext_vector_type(4)));

__device__ __forceinline__ float softplus_fast(float x) {
  return fmaxf(x, 0.f) + __logf(1.f + __expf(-fabsf(x)));
}
__device__ __forceinline__ float softplus_ref(float x) {
  return fmaxf(x, 0.f) + log1pf(expf(-fabsf(x)));
}
__device__ __forceinline__ float wredsum(float x) {
  #pragma unroll
  for (int o = 32; o; o >>= 1) x += __shfl_xor(x, o, 64);
  return x;
}
__device__ __forceinline__ float wredmax(float x) {
  #pragma unroll
  for (int o = 32; o; o >>= 1) x = fmaxf(x, __shfl_xor(x, o, 64));
  return x;
}
__device__ __forceinline__ void global_load_lds16(const void* g, void* l) {
  __builtin_amdgcn_global_load_lds(
      (const __attribute__((address_space(1))) uint32_t*)g,
      (__attribute__((address_space(3))) uint32_t*)l, 16, 0, 0);
}

// ---------------- prep_small: scalars, a/b/g/d tables, zero hist + out ----------------
__global__ __launch_bounds__(256) void prep_small(
    const float* __restrict__ lz, const float* __restrict__ lw,
    const float* __restrict__ gamma, const float* __restrict__ delta,
    const float* __restrict__ pks, const float* __restrict__ Lp,
    float* __restrict__ consts, float* __restrict__ a_tab, float* __restrict__ b_tab,
    float* __restrict__ g_tab, float* __restrict__ d_tab,
    uint32_t* __restrict__ hist, float* __restrict__ out)
{
  int n = blockIdx.x * blockDim.x + threadIdx.x;
  float Lv = softplus_ref(Lp[0]);
  if (n == 0) out[0] = 0.f;
  if (n < NLAYERS*256) hist[n] = 0u;
  if (n < N1) {
    float z0 = lz[n*3], z1 = lz[n*3+1], z2 = lz[n*3+2];
    float m = fmaxf(z0, fmaxf(z1, z2));
    float e0 = expf(z0-m), e1 = expf(z1-m), e2 = expf(z2-m);
    float inv = 1.f/(e0+e1+e2);
    a_tab[0*N1+n] = e0*inv*Lv; a_tab[1*N1+n] = e1*inv*Lv; a_tab[2*N1+n] = e2*inv*Lv;
    float w0 = lw[n*3], w1 = lw[n*3+1], w2 = lw[n*3+2];
    m = fmaxf(w0, fmaxf(w1, w2));
    e0 = expf(w0-m); e1 = expf(w1-m); e2 = expf(w2-m);
    inv = 1.f/(e0+e1+e2);
    b_tab[0*N2+n] = e0*inv+EPSV; b_tab[1*N2+n] = e1*inv+EPSV; b_tab[2*N2+n] = e2*inv+EPSV;
    #pragma unroll
    for (int k = 0; k < 3; ++k) {
      g_tab[k*N1+n] = gamma[n*3+k];
      d_tab[k*N2+n] = delta[n*3+k];
    }
  }
  if (n < NLAYERS) {
    float p[KKC+1]; float m = -1e30f;
    for (int k = 0; k <= KKC; ++k) { p[k] = pks[n*(KKC+1)+k]; m = fmaxf(m, p[k]); }
    float s = 0.f;
    for (int k = 0; k <= KKC; ++k) { p[k] = expf(p[k]-m); s += p[k]; }
    float inv = 1.f/s;
    for (int k = 0; k <= KKC; ++k) consts[8 + n*(KKC+1) + k] = p[k]*inv;
    consts[n] = p[0]*inv + EPSV*(1.f - p[0]*inv);  // c = p0 + EPS*(1-p0)
  }
}

// ---------------- edge binning: hist -> scan -> scatter ----------------
__global__ __launch_bounds__(256) void edge_hist(
    const int* __restrict__ is_, const int* __restrict__ js_,
    uint32_t* __restrict__ hist, int E)
{
  const int lay = blockIdx.y;
  const int e = blockIdx.x*256 + threadIdx.x;
  if (e < E) {
    int i = is_[(size_t)lay*E + e], j = js_[(size_t)lay*E + e];
    atomicAdd(&hist[lay*256 + (i>>8)*16 + (j>>8)], 1u);
  }
}

__global__ __launch_bounds__(256) void edge_scan(
    const uint32_t* __restrict__ hist, uint32_t* __restrict__ off,
    uint32_t* __restrict__ cursor)
{
  __shared__ uint32_t sa[768], sb[768];
  const int t = threadIdx.x;
  for (int i = t; i < 768; i += 256) sa[i] = hist[i];
  __syncthreads();
  uint32_t* src = sa; uint32_t* dst = sb;
  for (int s = 1; s < 768; s <<= 1) {
    for (int i = t; i < 768; i += 256) dst[i] = src[i] + (i >= s ? src[i-s] : 0u);
    __syncthreads();
    uint32_t* tmp = src; src = dst; dst = tmp;
  }
  for (int i = t; i < 768; i += 256) {
    uint32_t ex = i ? src[i-1] : 0u;
    off[i] = ex; cursor[i] = ex;
  }
  if (t == 0) off[768] = src[767];
}

__global__ __launch_bounds__(256) void edge_scatter(
    const int* __restrict__ is_, const int* __restrict__ js_,
    uint32_t* __restrict__ cursor, uint16_t* __restrict__ ebuf, int E)
{
  const int lay = blockIdx.y;
  const int e = blockIdx.x*256 + threadIdx.x;
  if (e < E) {
    int i = is_[(size_t)lay*E + e], j = js_[(size_t)lay*E + e];
    int bin = lay*256 + (i>>8)*16 + (j>>8);
    uint32_t pos = atomicAdd(&cursor[bin], 1u);
    ebuf[pos] = (uint16_t)(((i & 255) << 8) | (j & 255));
  }
}

// ---------------- prep_rows: wave-per-row softmax (+pyramid for z) ----------------
__global__ __launch_bounds__(256) void prep_rows(
    const float* __restrict__ us, const float* __restrict__ vs,
    bf16_t* __restrict__ zt, bf16_t* __restrict__ wt, size_t lstride,
    const float* __restrict__ consts, int layer0)
{
  const int t = threadIdx.x, w = t >> 6, l = t & 63;
  const int n = blockIdx.x*4 + w;
  const int layer = layer0 + blockIdx.y;
  const int zmode = (blockIdx.z == 0);
  const float* src = (zmode ? us : vs) + ((size_t)layer*N1 + n)*DD + l*16;
  bf16_t* dst = (zmode ? zt : wt) + (size_t)blockIdx.y*lstride + (size_t)n*DD + l*16;

  float e[16];
  {
    const float4* s4 = (const float4*)src;
    float4 u0 = s4[0], u1 = s4[1], u2 = s4[2], u3 = s4[3];
    e[0]=u0.x; e[1]=u0.y; e[2]=u0.z; e[3]=u0.w;
    e[4]=u1.x; e[5]=u1.y; e[6]=u1.z; e[7]=u1.w;
    e[8]=u2.x; e[9]=u2.y; e[10]=u2.z; e[11]=u2.w;
    e[12]=u3.x; e[13]=u3.y; e[14]=u3.z; e[15]=u3.w;
  }
  float mx = e[0];
  #pragma unroll
  for (int i = 1; i < 16; ++i) mx = fmaxf(mx, e[i]);
  mx = wredmax(mx);
  float s = 0.f;
  #pragma unroll
  for (int i = 0; i < 16; ++i) { e[i] = __expf(e[i]-mx); s += e[i]; }
  s = wredsum(s);
  float inv = 1.f/s;
  #pragma unroll
  for (int i = 0; i < 16; ++i) e[i] *= inv;

  if (!zmode) {
    bf16x8 o0, o1;
    #pragma unroll
    for (int i = 0; i < 8; ++i) { o0[i] = (bf16_t)e[i]; o1[i] = (bf16_t)e[8+i]; }
    *(bf16x8*)dst = o0; *(bf16x8*)(dst+8) = o1;
    return;
  }
  float s1[8], s2[4], s3[2], s4v;
  #pragma unroll
  for (int i = 0; i < 8; ++i) s1[i] = e[2*i] + e[2*i+1];
  #pragma unroll
  for (int i = 0; i < 4; ++i) s2[i] = s1[2*i] + s1[2*i+1];
  s3[0] = s2[0]+s2[1]; s3[1] = s2[2]+s2[3];
  s4v = s3[0]+s3[1];
  float s5 = s4v + __shfl_xor(s4v, 1, 64);
  float s6 = s5  + __shfl_xor(s5, 2, 64);
  float s7 = s6  + __shfl_xor(s6, 4, 64);
  float s8 = s7  + __shfl_xor(s7, 8, 64);
  float s9 = s8  + __shfl_xor(s8, 16, 64);
  const float* pk = consts + 8 + layer*(KKC+1);
  const float base = pk[4]*s4v + pk[5]*s5 + pk[6]*s6 + pk[7]*s7 + pk[8]*s8 + pk[9]*s9;
  const float p1 = pk[1], p2 = pk[2], p3 = pk[3], p10 = pk[10];
  bf16x8 o0, o1;
  #pragma unroll
  for (int i = 0; i < 8; ++i) {
    o0[i] = (bf16_t)(p10*e[i]   + p1*s1[i>>1]     + p2*s2[i>>2]     + p3*s3[i>>3]     + base);
    o1[i] = (bf16_t)(p10*e[8+i] + p1*s1[(8+i)>>1] + p2*s2[(8+i)>>2] + p3*s3[1]        + base);
  }
  *(bf16x8*)dst = o0; *(bf16x8*)(dst+8) = o1;
}

// ---------------- 256x256 GEMM: single-barrier phases + fused dense & sparse epilogue ----------------
// 8 waves (2Mx4N), wave tile 128x64. BK=64, 2 LDS bufs x 64KB {A[256][64], B[256][64]},
// granule-XOR swizzle g^(row&7) both-sides. 4 phases/tile, ONE s_barrier per phase
// (waves may slip one segment; ledger-verified WAR-safe stage map):
//   P1: LDA(mq0)+LDB(nq0); STG B1[u+1](other buf);            BAR; MFMA(0,0)
//   P2: LDB(nq1);          STG A0[u+1](other buf);            BAR; MFMA(0,1)
//   P3: LDA(mq1);          STG A1[u+1](other buf);            BAR; MFMA(1,0)
//   P4:                    STG B0[u+2](cur buf, B reads drained); vmcnt(2); BAR; MFMA(1,1)
// vmcnt(2) retires exactly tile u+1 (B0[u+1] was issued at u-1 P4); vmcnt(0) only at u=14.
__global__ __launch_bounds__(512, 2) void gemm_fused(
    const bf16_t* __restrict__ Az, size_t zls,
    const bf16_t* __restrict__ Bw, size_t wls,
    const float* __restrict__ a_tab, const float* __restrict__ b_tab,
    const float* __restrict__ g_tab, const float* __restrict__ d_tab,
    const float* __restrict__ consts, int layer0,
    const uint32_t* __restrict__ eoff, const uint16_t* __restrict__ ebuf,
    float* __restrict__ out)
{
  extern __shared__ char lds[];                // 2 x 64KB
  const int t = threadIdx.x;
  const int w = t >> 6, l = t & 63;
  const int wm = w >> 2, wn = w & 3;
  const int fr = l & 15, fq = l >> 4;

  // T1: bijective XCD swizzle (nblk % 8 == 0)
  const int nbx = gridDim.x, nby = gridDim.y;
  int lid = blockIdx.x + nbx*(blockIdx.y + nby*blockIdx.z);
  const int nblk = nbx*nby*gridDim.z;
  const int cpx = nblk >> 3;
  int nid = (lid & 7)*cpx + (lid >> 3);
  const int bz = nid / (nbx*nby);
  const int rem = nid % (nbx*nby);
  const int bi = rem % nbx, bj = rem / nbx;

  const int i0 = bi*256, j0 = bj*256;
  const int layer = layer0 + bz;
  Az += (size_t)bz*zls + (size_t)i0*DD;
  Bw += (size_t)bz*wls + (size_t)j0*DD;

  f32x4 acc[8][4];
  f32x4 zero = {0.f, 0.f, 0.f, 0.f};
  #pragma unroll
  for (int m = 0; m < 8; ++m)
    #pragma unroll
    for (int nn = 0; nn < 4; ++nn) acc[m][nn] = zero;

  const int srow = w*8 + (l >> 3);
  const int sgs  = (l & 7) ^ (srow & 7);
  const size_t so0 = (size_t)srow*DD + (size_t)sgs*8;
  const size_t so1 = so0 + (size_t)64*DD;
  const int sx = fr & 7;
  const int aofs0 = wm*16384 + fr*128 + ((0+fq)^sx)*16;
  const int aofs1 = wm*16384 + fr*128 + ((4+fq)^sx)*16;
  const int bofs0 = 32768 + wn*8192 + fr*128 + ((0+fq)^sx)*16;
  const int bofs1 = 32768 + wn*8192 + fr*128 + ((4+fq)^sx)*16;

  bf16x8 ar[8], br[8];

#define STG(matptr, matofs, half, tile) do { \
    const bf16_t* _s = (matptr) + (size_t)(half)*128*DD + (size_t)(tile)*64; \
    char* _d = lds + ((tile)&1)*65536 + (matofs) + (half)*16384 + w*1024; \
    global_load_lds16(_s + so0, _d); \
    global_load_lds16(_s + so1, _d + 8192); \
  } while (0)
#define LDA(bufb, mq) do { \
    const char* _b = lds + (bufb); \
    _Pragma("unroll") for (int i = 0; i < 4; ++i) { \
      ar[i]   = *(const bf16x8*)(_b + aofs0 + ((mq)*4+i)*2048); \
      ar[4+i] = *(const bf16x8*)(_b + aofs1 + ((mq)*4+i)*2048); } \
  } while (0)
#define LDB(bufb, nq) do { \
    const char* _b = lds + (bufb); \
    _Pragma("unroll") for (int j = 0; j < 2; ++j) { \
      br[(nq)*2+j]   = *(const bf16x8*)(_b + bofs0 + ((nq)*2+j)*2048); \
      br[4+(nq)*2+j] = *(const bf16x8*)(_b + bofs1 + ((nq)*2+j)*2048); } \
  } while (0)
#define MM(mq, nq) do { \
    _Pragma("unroll") for (int k = 0; k < 2; ++k) \
    _Pragma("unroll") for (int i = 0; i < 4; ++i) \
    _Pragma("unroll") for (int j = 0; j < 2; ++j) \
      acc[(mq)*4+i][(nq)*2+j] = __builtin_amdgcn_mfma_f32_16x16x32_bf16( \
          ar[k*4+i], br[k*4+(nq)*2+j], acc[(mq)*4+i][(nq)*2+j], 0, 0, 0); \
  } while (0)
#define BAR() asm volatile("s_barrier" ::: "memory")
#define PRIO_MM(mq, nq) do { \
    __builtin_amdgcn_s_setprio(1); MM(mq, nq); __builtin_amdgcn_s_setprio(0); } while (0)

  // prologue: tile0 fully + B0[1]; retire tile0, keep B0[1] in flight
  STG(Az, 0, 0, 0); STG(Az, 0, 1, 0); STG(Bw, 32768, 0, 0); STG(Bw, 32768, 1, 0);
  STG(Bw, 32768, 0, 1);
  asm volatile("s_waitcnt vmcnt(2)" ::: "memory");
  BAR();

  #pragma unroll 2
  for (int u = 0; u < 16; ++u) {
    const int cb = (u & 1)*65536;
    // P1
    LDA(cb, 0); LDB(cb, 0);
    if (u < 15) STG(Bw, 32768, 1, u+1);
    BAR(); PRIO_MM(0, 0);
    // P2
    LDB(cb, 1);
    if (u < 15) STG(Az, 0, 0, u+1);
    BAR(); PRIO_MM(0, 1);
    // P3
    LDA(cb, 1);
    if (u < 15) STG(Az, 0, 1, u+1);
    BAR(); PRIO_MM(1, 0);
    // P4
    if (u < 14) {
      STG(Bw, 32768, 0, u+2);
      asm volatile("s_waitcnt vmcnt(2)" ::: "memory");
    } else if (u == 14) {
      asm volatile("s_waitcnt vmcnt(0)" ::: "memory");
    }
    BAR(); PRIO_MM(1, 1);
  }
#undef STG
#undef LDA
#undef LDB
#undef MM
#undef BAR
#undef PRIO_MM

  // ---- epilogue: stage C (bf16, +cc) into LDS 256x512B; dense softplus-sum + binned sparse sum ----
  const float cc = consts[layer];
  {
    char* cbase = lds + wm*65536 + fq*2048 + wn*128 + fr*2;
    #pragma unroll
    for (int m = 0; m < 8; ++m)
      #pragma unroll
      for (int nn = 0; nn < 4; ++nn)
        #pragma unroll
        for (int r = 0; r < 4; ++r)
          *(bf16_t*)(cbase + m*8192 + r*512 + nn*32) = (bf16_t)(acc[m][nn][r] + cc);
  }
  __syncthreads();

  const float* at = a_tab + layer*N1;
  const float* bt = b_tab + layer*N2;
  const float* gt = g_tab + layer*N1;
  const float* dt = d_tab + layer*N2;
  float dsum = 0.f;
  #pragma unroll 4
  for (int i = 0; i < 16; ++i) {
    const int id = t + i*512;
    const int row = id >> 5, g = id & 31;
    bf16x8 v = *(const bf16x8*)(lds + row*512 + g*16);
    const int grow = i0 + row, gcol = j0 + g*8;
    const float av = at[grow], gv = gt[grow];
    float4 b0 = *(const float4*)(bt + gcol), b1 = *(const float4*)(bt + gcol + 4);
    float4 d0 = *(const float4*)(dt + gcol), d1 = *(const float4*)(dt + gcol + 4);
    float bb[8] = {b0.x,b0.y,b0.z,b0.w,b1.x,b1.y,b1.z,b1.w};
    float dd[8] = {d0.x,d0.y,d0.z,d0.w,d1.x,d1.y,d1.z,d1.w};
    #pragma unroll
    for (int e2 = 0; e2 < 8; ++e2) {
      float x = av*bb[e2]*(float)v[e2] + gv + dd[e2];
      float sp = softplus_fast(x);
      dsum += (grow != gcol + e2) ? sp : 0.f;
    }
  }
  // sparse: edges of this (layer, tile) bin, gathered from LDS C
  const int bin = bz*256 + bi*16 + bj;
  const uint32_t e0 = eoff[bin], e1 = eoff[bin+1];
  float ssum = 0.f;
  for (uint32_t e = e0 + (uint32_t)t; e < e1; e += 512u) {
    const int pk2 = ebuf[e];
    const int li = pk2 >> 8, lj = pk2 & 255;
    float dc = (float)*(const bf16_t*)(lds + li*512 + lj*2);
    ssum += at[i0+li]*bt[j0+lj]*dc + gt[i0+li] + dt[j0+lj];
  }
  float tot = wredsum(ssum - dsum);
  __syncthreads();
  if (l == 0) ((float*)lds)[w] = tot;
  __syncthreads();
  if (t == 0) {
    const float* r = (const float*)lds;
    float s = 0.f;
    #pragma unroll
    for (int i = 0; i < 8; ++i) s += r[i];
    atomicAdd(out, s);   // ll += z_pdist2 - z_pdist1
  }
}

extern "C" void kernel_launch(void* const* d_in, const int* in_sizes, int n_in,
                              void* d_out, int out_size, void* d_ws, size_t ws_size,
                              hipStream_t stream) {
  const float* us    = (const float*)d_in[0];
  const float* vs    = (const float*)d_in[1];
  const float* gamma = (const float*)d_in[2];
  const float* delta = (const float*)d_in[3];
  const float* lz    = (const float*)d_in[4];
  const float* lw    = (const float*)d_in[5];
  const float* pks   = (const float*)d_in[6];
  const float* Lp    = (const float*)d_in[7];
  const int*   sis   = (const int*)d_in[8];
  const int*   sjs   = (const int*)d_in[9];
  float* out = (float*)d_out;
  char*  ws  = (char*)d_ws;
  const int E = in_sizes[8] / NLAYERS;

  // runtime ws layout
  size_t p = 0;
  float* consts = (float*)(ws + p); p += 1024;
  float* a_tab  = (float*)(ws + p); p += (size_t)NLAYERS*N1*4;
  float* b_tab  = (float*)(ws + p); p += (size_t)NLAYERS*N2*4;
  float* g_tab  = (float*)(ws + p); p += (size_t)NLAYERS*N1*4;
  float* d_tab  = (float*)(ws + p); p += (size_t)NLAYERS*N2*4;
  uint32_t* hist   = (uint32_t*)(ws + p); p += 1024*4;        // 768 used
  uint32_t* eoff   = (uint32_t*)(ws + p); p += 1024*4;        // 769 used
  uint32_t* cursor = (uint32_t*)(ws + p); p += 1024*4;        // 768 used
  uint16_t* ebuf   = (uint16_t*)(ws + p); p += (size_t)NLAYERS*E*2;
  p = (p + 4095) & ~(size_t)4095;
  bf16_t* zt = (bf16_t*)(ws + p); p += (size_t)NLAYERS*N1*DD*2;
  bf16_t* wt = (bf16_t*)(ws + p); p += (size_t)NLAYERS*N2*DD*2;
  if (ws_size < p) return;
  const size_t ZLS = (size_t)N1*DD;
  const size_t LDSB = 131072;

  prep_small<<<(N1+255)/256, 256, 0, stream>>>(lz, lw, gamma, delta, pks, Lp,
                                               consts, a_tab, b_tab, g_tab, d_tab,
                                               hist, out);
  edge_hist<<<dim3((E+255)/256, NLAYERS), 256, 0, stream>>>(sis, sjs, hist, E);
  edge_scan<<<1, 256, 0, stream>>>(hist, eoff, cursor);
  edge_scatter<<<dim3((E+255)/256, NLAYERS), 256, 0, stream>>>(sis, sjs, cursor, ebuf, E);
  prep_rows<<<dim3(N1/4, NLAYERS, 2), 256, 0, stream>>>(us, vs, zt, wt, ZLS, consts, 0);
  gemm_fused<<<dim3(16,16,NLAYERS), 512, LDSB, stream>>>(
      zt, ZLS, wt, ZLS, a_tab, b_tab, g_tab, d_tab, consts, 0, eoff, ebuf, out);
}

// Round 9
// 166.154 us; speedup vs baseline: 3.5085x; 3.5085x over previous
//
#include <hip/hip_runtime.h>
#include <hip/hip_bf16.h>
#include <stdint.h>

#define EPSV 1e-6f
#define N1 4096
#define N2 4096
#define DD 1024
#define NLAYERS 3
#define KKC 10

typedef __bf16 bf16_t;
typedef __bf16 bf16x8 __attribute__((ext_vector_type(8)));
typedef float f32x4 __attribute__((ext_vector_type(4)));

__device__ __forceinline__ float softplus_fast(float x) {
  return fmaxf(x, 0.f) + __logf(1.f + __expf(-fabsf(x)));
}
__device__ __forceinline__ float softplus_ref(float x) {
  return fmaxf(x, 0.f) + log1pf(expf(-fabsf(x)));
}
__device__ __forceinline__ float wredsum(float x) {
  #pragma unroll
  for (int o = 32; o; o >>= 1) x += __shfl_xor(x, o, 64);
  return x;
}
__device__ __forceinline__ float wredmax(float x) {
  #pragma unroll
  for (int o = 32; o; o >>= 1) x = fmaxf(x, __shfl_xor(x, o, 64));
  return x;
}
__device__ __forceinline__ void global_load_lds16(const void* g, void* l) {
  __builtin_amdgcn_global_load_lds(
      (const __attribute__((address_space(1))) uint32_t*)g,
      (__attribute__((address_space(3))) uint32_t*)l, 16, 0, 0);
}

// ---------------- prep_small: scalars, a/b/g/d tables, zero hist + out ----------------
__global__ __launch_bounds__(256) void prep_small(
    const float* __restrict__ lz, const float* __restrict__ lw,
    const float* __restrict__ gamma, const float* __restrict__ delta,
    const float* __restrict__ pks, const float* __restrict__ Lp,
    float* __restrict__ consts, float* __restrict__ a_tab, float* __restrict__ b_tab,
    float* __restrict__ g_tab, float* __restrict__ d_tab,
    uint32_t* __restrict__ hist, float* __restrict__ out)
{
  int n = blockIdx.x * blockDim.x + threadIdx.x;
  float Lv = softplus_ref(Lp[0]);
  if (n == 0) out[0] = 0.f;
  if (n < NLAYERS*256) hist[n] = 0u;
  if (n < N1) {
    float z0 = lz[n*3], z1 = lz[n*3+1], z2 = lz[n*3+2];
    float m = fmaxf(z0, fmaxf(z1, z2));
    float e0 = expf(z0-m), e1 = expf(z1-m), e2 = expf(z2-m);
    float inv = 1.f/(e0+e1+e2);
    a_tab[0*N1+n] = e0*inv*Lv; a_tab[1*N1+n] = e1*inv*Lv; a_tab[2*N1+n] = e2*inv*Lv;
    float w0 = lw[n*3], w1 = lw[n*3+1], w2 = lw[n*3+2];
    m = fmaxf(w0, fmaxf(w1, w2));
    e0 = expf(w0-m); e1 = expf(w1-m); e2 = expf(w2-m);
    inv = 1.f/(e0+e1+e2);
    b_tab[0*N2+n] = e0*inv+EPSV; b_tab[1*N2+n] = e1*inv+EPSV; b_tab[2*N2+n] = e2*inv+EPSV;
    #pragma unroll
    for (int k = 0; k < 3; ++k) {
      g_tab[k*N1+n] = gamma[n*3+k];
      d_tab[k*N2+n] = delta[n*3+k];
    }
  }
  if (n < NLAYERS) {
    float p[KKC+1]; float m = -1e30f;
    for (int k = 0; k <= KKC; ++k) { p[k] = pks[n*(KKC+1)+k]; m = fmaxf(m, p[k]); }
    float s = 0.f;
    for (int k = 0; k <= KKC; ++k) { p[k] = expf(p[k]-m); s += p[k]; }
    float inv = 1.f/s;
    for (int k = 0; k <= KKC; ++k) consts[8 + n*(KKC+1) + k] = p[k]*inv;
    consts[n] = p[0]*inv + EPSV*(1.f - p[0]*inv);  // c = p0 + EPS*(1-p0)
  }
}

// ---------------- edge binning: LDS-aggregated hist -> scan -> range-reserve scatter ----------------
#define EPB 2048   // edges per block

__global__ __launch_bounds__(256) void edge_hist(
    const int* __restrict__ is_, const int* __restrict__ js_,
    uint32_t* __restrict__ hist, int E)
{
  __shared__ uint32_t h[256];
  const int lay = blockIdx.y;
  const int t = threadIdx.x;
  h[t] = 0u;
  __syncthreads();
  const int e0 = blockIdx.x * EPB;
  const int e1 = min(e0 + EPB, E);
  for (int e = e0 + t; e < e1; e += 256) {
    int i = is_[(size_t)lay*E + e], j = js_[(size_t)lay*E + e];
    atomicAdd(&h[(i>>8)*16 + (j>>8)], 1u);
  }
  __syncthreads();
  if (h[t]) atomicAdd(&hist[lay*256 + t], h[t]);
}

__global__ __launch_bounds__(256) void edge_scan(
    const uint32_t* __restrict__ hist, uint32_t* __restrict__ off,
    uint32_t* __restrict__ cursor)
{
  __shared__ uint32_t sa[768], sb[768];
  const int t = threadIdx.x;
  for (int i = t; i < 768; i += 256) sa[i] = hist[i];
  __syncthreads();
  uint32_t* src = sa; uint32_t* dst = sb;
  for (int s = 1; s < 768; s <<= 1) {
    for (int i = t; i < 768; i += 256) dst[i] = src[i] + (i >= s ? src[i-s] : 0u);
    __syncthreads();
    uint32_t* tmp = src; src = dst; dst = tmp;
  }
  for (int i = t; i < 768; i += 256) {
    uint32_t ex = i ? src[i-1] : 0u;
    off[i] = ex; cursor[i] = ex;
  }
  if (t == 0) off[768] = src[767];
}

__global__ __launch_bounds__(256) void edge_scatter(
    const int* __restrict__ is_, const int* __restrict__ js_,
    uint32_t* __restrict__ cursor, uint16_t* __restrict__ ebuf, int E)
{
  __shared__ uint32_t h[256];
  __shared__ uint32_t basev[256];
  const int lay = blockIdx.y;
  const int t = threadIdx.x;
  h[t] = 0u;
  __syncthreads();
  const int e0 = blockIdx.x * EPB;
  const int e1 = min(e0 + EPB, E);
  // phase A: block-local histogram
  for (int e = e0 + t; e < e1; e += 256) {
    int i = is_[(size_t)lay*E + e], j = js_[(size_t)lay*E + e];
    atomicAdd(&h[(i>>8)*16 + (j>>8)], 1u);
  }
  __syncthreads();
  // phase B: reserve contiguous ranges in each bin (one global atomic per bin per block)
  basev[t] = h[t] ? atomicAdd(&cursor[lay*256 + t], h[t]) : 0u;
  h[t] = 0u;   // reuse as block-local rank cursor
  __syncthreads();
  // phase C: re-read edges (L2-hot), rank via LDS atomic, write packed coords
  for (int e = e0 + t; e < e1; e += 256) {
    int i = is_[(size_t)lay*E + e], j = js_[(size_t)lay*E + e];
    int b = (i>>8)*16 + (j>>8);
    uint32_t r = atomicAdd(&h[b], 1u);
    ebuf[basev[b] + r] = (uint16_t)(((i & 255) << 8) | (j & 255));
  }
}

// ---------------- prep_rows: wave-per-row softmax (+pyramid for z) ----------------
__global__ __launch_bounds__(256) void prep_rows(
    const float* __restrict__ us, const float* __restrict__ vs,
    bf16_t* __restrict__ zt, bf16_t* __restrict__ wt, size_t lstride,
    const float* __restrict__ consts, int layer0)
{
  const int t = threadIdx.x, w = t >> 6, l = t & 63;
  const int n = blockIdx.x*4 + w;
  const int layer = layer0 + blockIdx.y;
  const int zmode = (blockIdx.z == 0);
  const float* src = (zmode ? us : vs) + ((size_t)layer*N1 + n)*DD + l*16;
  bf16_t* dst = (zmode ? zt : wt) + (size_t)blockIdx.y*lstride + (size_t)n*DD + l*16;

  float e[16];
  {
    const float4* s4 = (const float4*)src;
    float4 u0 = s4[0], u1 = s4[1], u2 = s4[2], u3 = s4[3];
    e[0]=u0.x; e[1]=u0.y; e[2]=u0.z; e[3]=u0.w;
    e[4]=u1.x; e[5]=u1.y; e[6]=u1.z; e[7]=u1.w;
    e[8]=u2.x; e[9]=u2.y; e[10]=u2.z; e[11]=u2.w;
    e[12]=u3.x; e[13]=u3.y; e[14]=u3.z; e[15]=u3.w;
  }
  float mx = e[0];
  #pragma unroll
  for (int i = 1; i < 16; ++i) mx = fmaxf(mx, e[i]);
  mx = wredmax(mx);
  float s = 0.f;
  #pragma unroll
  for (int i = 0; i < 16; ++i) { e[i] = __expf(e[i]-mx); s += e[i]; }
  s = wredsum(s);
  float inv = 1.f/s;
  #pragma unroll
  for (int i = 0; i < 16; ++i) e[i] *= inv;

  if (!zmode) {
    bf16x8 o0, o1;
    #pragma unroll
    for (int i = 0; i < 8; ++i) { o0[i] = (bf16_t)e[i]; o1[i] = (bf16_t)e[8+i]; }
    *(bf16x8*)dst = o0; *(bf16x8*)(dst+8) = o1;
    return;
  }
  float s1[8], s2[4], s3[2], s4v;
  #pragma unroll
  for (int i = 0; i < 8; ++i) s1[i] = e[2*i] + e[2*i+1];
  #pragma unroll
  for (int i = 0; i < 4; ++i) s2[i] = s1[2*i] + s1[2*i+1];
  s3[0] = s2[0]+s2[1]; s3[1] = s2[2]+s2[3];
  s4v = s3[0]+s3[1];
  float s5 = s4v + __shfl_xor(s4v, 1, 64);
  float s6 = s5  + __shfl_xor(s5, 2, 64);
  float s7 = s6  + __shfl_xor(s6, 4, 64);
  float s8 = s7  + __shfl_xor(s7, 8, 64);
  float s9 = s8  + __shfl_xor(s8, 16, 64);
  const float* pk = consts + 8 + layer*(KKC+1);
  const float base = pk[4]*s4v + pk[5]*s5 + pk[6]*s6 + pk[7]*s7 + pk[8]*s8 + pk[9]*s9;
  const float p1 = pk[1], p2 = pk[2], p3 = pk[3], p10 = pk[10];
  bf16x8 o0, o1;
  #pragma unroll
  for (int i = 0; i < 8; ++i) {
    o0[i] = (bf16_t)(p10*e[i]   + p1*s1[i>>1]     + p2*s2[i>>2]     + p3*s3[i>>3]     + base);
    o1[i] = (bf16_t)(p10*e[8+i] + p1*s1[(8+i)>>1] + p2*s2[(8+i)>>2] + p3*s3[1]        + base);
  }
  *(bf16x8*)dst = o0; *(bf16x8*)(dst+8) = o1;
}

// ---------------- 256x256 GEMM: single-barrier phases + fused dense & sparse epilogue ----------------
// (byte-identical K-loop/epilogue to R8)
__global__ __launch_bounds__(512, 2) void gemm_fused(
    const bf16_t* __restrict__ Az, size_t zls,
    const bf16_t* __restrict__ Bw, size_t wls,
    const float* __restrict__ a_tab, const float* __restrict__ b_tab,
    const float* __restrict__ g_tab, const float* __restrict__ d_tab,
    const float* __restrict__ consts, int layer0,
    const uint32_t* __restrict__ eoff, const uint16_t* __restrict__ ebuf,
    float* __restrict__ out)
{
  extern __shared__ char lds[];                // 2 x 64KB
  const int t = threadIdx.x;
  const int w = t >> 6, l = t & 63;
  const int wm = w >> 2, wn = w & 3;
  const int fr = l & 15, fq = l >> 4;

  const int nbx = gridDim.x, nby = gridDim.y;
  int lid = blockIdx.x + nbx*(blockIdx.y + nby*blockIdx.z);
  const int nblk = nbx*nby*gridDim.z;
  const int cpx = nblk >> 3;
  int nid = (lid & 7)*cpx + (lid >> 3);
  const int bz = nid / (nbx*nby);
  const int rem = nid % (nbx*nby);
  const int bi = rem % nbx, bj = rem / nbx;

  const int i0 = bi*256, j0 = bj*256;
  const int layer = layer0 + bz;
  Az += (size_t)bz*zls + (size_t)i0*DD;
  Bw += (size_t)bz*wls + (size_t)j0*DD;

  f32x4 acc[8][4];
  f32x4 zero = {0.f, 0.f, 0.f, 0.f};
  #pragma unroll
  for (int m = 0; m < 8; ++m)
    #pragma unroll
    for (int nn = 0; nn < 4; ++nn) acc[m][nn] = zero;

  const int srow = w*8 + (l >> 3);
  const int sgs  = (l & 7) ^ (srow & 7);
  const size_t so0 = (size_t)srow*DD + (size_t)sgs*8;
  const size_t so1 = so0 + (size_t)64*DD;
  const int sx = fr & 7;
  const int aofs0 = wm*16384 + fr*128 + ((0+fq)^sx)*16;
  const int aofs1 = wm*16384 + fr*128 + ((4+fq)^sx)*16;
  const int bofs0 = 32768 + wn*8192 + fr*128 + ((0+fq)^sx)*16;
  const int bofs1 = 32768 + wn*8192 + fr*128 + ((4+fq)^sx)*16;

  bf16x8 ar[8], br[8];

#define STG(matptr, matofs, half, tile) do { \
    const bf16_t* _s = (matptr) + (size_t)(half)*128*DD + (size_t)(tile)*64; \
    char* _d = lds + ((tile)&1)*65536 + (matofs) + (half)*16384 + w*1024; \
    global_load_lds16(_s + so0, _d); \
    global_load_lds16(_s + so1, _d + 8192); \
  } while (0)
#define LDA(bufb, mq) do { \
    const char* _b = lds + (bufb); \
    _Pragma("unroll") for (int i = 0; i < 4; ++i) { \
      ar[i]   = *(const bf16x8*)(_b + aofs0 + ((mq)*4+i)*2048); \
      ar[4+i] = *(const bf16x8*)(_b + aofs1 + ((mq)*4+i)*2048); } \
  } while (0)
#define LDB(bufb, nq) do { \
    const char* _b = lds + (bufb); \
    _Pragma("unroll") for (int j = 0; j < 2; ++j) { \
      br[(nq)*2+j]   = *(const bf16x8*)(_b + bofs0 + ((nq)*2+j)*2048); \
      br[4+(nq)*2+j] = *(const bf16x8*)(_b + bofs1 + ((nq)*2+j)*2048); } \
  } while (0)
#define MM(mq, nq) do { \
    _Pragma("unroll") for (int k = 0; k < 2; ++k) \
    _Pragma("unroll") for (int i = 0; i < 4; ++i) \
    _Pragma("unroll") for (int j = 0; j < 2; ++j) \
      acc[(mq)*4+i][(nq)*2+j] = __builtin_amdgcn_mfma_f32_16x16x32_bf16( \
          ar[k*4+i], br[k*4+(nq)*2+j], acc[(mq)*4+i][(nq)*2+j], 0, 0, 0); \
  } while (0)
#define BAR() asm volatile("s_barrier" ::: "memory")
#define PRIO_MM(mq, nq) do { \
    __builtin_amdgcn_s_setprio(1); MM(mq, nq); __builtin_amdgcn_s_setprio(0); } while (0)

  STG(Az, 0, 0, 0); STG(Az, 0, 1, 0); STG(Bw, 32768, 0, 0); STG(Bw, 32768, 1, 0);
  STG(Bw, 32768, 0, 1);
  asm volatile("s_waitcnt vmcnt(2)" ::: "memory");
  BAR();

  #pragma unroll 2
  for (int u = 0; u < 16; ++u) {
    const int cb = (u & 1)*65536;
    LDA(cb, 0); LDB(cb, 0);
    if (u < 15) STG(Bw, 32768, 1, u+1);
    BAR(); PRIO_MM(0, 0);
    LDB(cb, 1);
    if (u < 15) STG(Az, 0, 0, u+1);
    BAR(); PRIO_MM(0, 1);
    LDA(cb, 1);
    if (u < 15) STG(Az, 0, 1, u+1);
    BAR(); PRIO_MM(1, 0);
    if (u < 14) {
      STG(Bw, 32768, 0, u+2);
      asm volatile("s_waitcnt vmcnt(2)" ::: "memory");
    } else if (u == 14) {
      asm volatile("s_waitcnt vmcnt(0)" ::: "memory");
    }
    BAR(); PRIO_MM(1, 1);
  }
#undef STG
#undef LDA
#undef LDB
#undef MM
#undef BAR
#undef PRIO_MM

  const float cc = consts[layer];
  {
    char* cbase = lds + wm*65536 + fq*2048 + wn*128 + fr*2;
    #pragma unroll
    for (int m = 0; m < 8; ++m)
      #pragma unroll
      for (int nn = 0; nn < 4; ++nn)
        #pragma unroll
        for (int r = 0; r < 4; ++r)
          *(bf16_t*)(cbase + m*8192 + r*512 + nn*32) = (bf16_t)(acc[m][nn][r] + cc);
  }
  __syncthreads();

  const float* at = a_tab + layer*N1;
  const float* bt = b_tab + layer*N2;
  const float* gt = g_tab + layer*N1;
  const float* dt = d_tab + layer*N2;
  float dsum = 0.f;
  #pragma unroll 4
  for (int i = 0; i < 16; ++i) {
    const int id = t + i*512;
    const int row = id >> 5, g = id & 31;
    bf16x8 v = *(const bf16x8*)(lds + row*512 + g*16);
    const int grow = i0 + row, gcol = j0 + g*8;
    const float av = at[grow], gv = gt[grow];
    float4 b0 = *(const float4*)(bt + gcol), b1 = *(const float4*)(bt + gcol + 4);
    float4 d0 = *(const float4*)(dt + gcol), d1 = *(const float4*)(dt + gcol + 4);
    float bb[8] = {b0.x,b0.y,b0.z,b0.w,b1.x,b1.y,b1.z,b1.w};
    float dd[8] = {d0.x,d0.y,d0.z,d0.w,d1.x,d1.y,d1.z,d1.w};
    #pragma unroll
    for (int e2 = 0; e2 < 8; ++e2) {
      float x = av*bb[e2]*(float)v[e2] + gv + dd[e2];
      float sp = softplus_fast(x);
      dsum += (grow != gcol + e2) ? sp : 0.f;
    }
  }
  const int bin = bz*256 + bi*16 + bj;
  const uint32_t e0 = eoff[bin], e1 = eoff[bin+1];
  float ssum = 0.f;
  for (uint32_t e = e0 + (uint32_t)t; e < e1; e += 512u) {
    const int pk2 = ebuf[e];
    const int li = pk2 >> 8, lj = pk2 & 255;
    float dc = (float)*(const bf16_t*)(lds + li*512 + lj*2);
    ssum += at[i0+li]*bt[j0+lj]*dc + gt[i0+li] + dt[j0+lj];
  }
  float tot = wredsum(ssum - dsum);
  __syncthreads();
  if (l == 0) ((float*)lds)[w] = tot;
  __syncthreads();
  if (t == 0) {
    const float* r = (const float*)lds;
    float s = 0.f;
    #pragma unroll
    for (int i = 0; i < 8; ++i) s += r[i];
    atomicAdd(out, s);   // ll += z_pdist2 - z_pdist1
  }
}

extern "C" void kernel_launch(void* const* d_in, const int* in_sizes, int n_in,
                              void* d_out, int out_size, void* d_ws, size_t ws_size,
                              hipStream_t stream) {
  const float* us    = (const float*)d_in[0];
  const float* vs    = (const float*)d_in[1];
  const float* gamma = (const float*)d_in[2];
  const float* delta = (const float*)d_in[3];
  const float* lz    = (const float*)d_in[4];
  const float* lw    = (const float*)d_in[5];
  const float* pks   = (const float*)d_in[6];
  const float* Lp    = (const float*)d_in[7];
  const int*   sis   = (const int*)d_in[8];
  const int*   sjs   = (const int*)d_in[9];
  float* out = (float*)d_out;
  char*  ws  = (char*)d_ws;
  const int E = in_sizes[8] / NLAYERS;

  size_t p = 0;
  float* consts = (float*)(ws + p); p += 1024;
  float* a_tab  = (float*)(ws + p); p += (size_t)NLAYERS*N1*4;
  float* b_tab  = (float*)(ws + p); p += (size_t)NLAYERS*N2*4;
  float* g_tab  = (float*)(ws + p); p += (size_t)NLAYERS*N1*4;
  float* d_tab  = (float*)(ws + p); p += (size_t)NLAYERS*N2*4;
  uint32_t* hist   = (uint32_t*)(ws + p); p += 1024*4;
  uint32_t* eoff   = (uint32_t*)(ws + p); p += 1024*4;
  uint32_t* cursor = (uint32_t*)(ws + p); p += 1024*4;
  uint16_t* ebuf   = (uint16_t*)(ws + p); p += (size_t)NLAYERS*E*2;
  p = (p + 4095) & ~(size_t)4095;
  bf16_t* zt = (bf16_t*)(ws + p); p += (size_t)NLAYERS*N1*DD*2;
  bf16_t* wt = (bf16_t*)(ws + p); p += (size_t)NLAYERS*N2*DD*2;
  if (ws_size < p) return;
  const size_t ZLS = (size_t)N1*DD;
  const size_t LDSB = 131072;
  const int nebl = (E + EPB - 1) / EPB;

  prep_small<<<(N1+255)/256, 256, 0, stream>>>(lz, lw, gamma, delta, pks, Lp,
                                               consts, a_tab, b_tab, g_tab, d_tab,
                                               hist, out);
  edge_hist<<<dim3(nebl, NLAYERS), 256, 0, stream>>>(sis, sjs, hist, E);
  edge_scan<<<1, 256, 0, stream>>>(hist, eoff, cursor);
  edge_scatter<<<dim3(nebl, NLAYERS), 256, 0, stream>>>(sis, sjs, cursor, ebuf, E);
  prep_rows<<<dim3(N1/4, NLAYERS, 2), 256, 0, stream>>>(us, vs, zt, wt, ZLS, consts, 0);
  gemm_fused<<<dim3(16,16,NLAYERS), 512, LDSB, stream>>>(
      zt, ZLS, wt, ZLS, a_tab, b_tab, g_tab, d_tab, consts, 0, eoff, ebuf, out);
}

// Round 10
// 154.997 us; speedup vs baseline: 3.7610x; 1.0720x over previous
//
#include <hip/hip_runtime.h>
#include <hip/hip_bf16.h>
#include <stdint.h>

#define EPSV 1e-6f
#define N1 4096
#define N2 4096
#define DD 1024
#define NLAYERS 3
#define KKC 10

typedef __bf16 bf16_t;
typedef __bf16 bf16x8 __attribute__((ext_vector_type(8)));
typedef float f32x4 __attribute__((ext_vector_type(4)));

#define ZSCALE 256.0f
#define WSCALE 64.0f
#define INVSCALE 6.103515625e-05f   // 1/(ZSCALE*WSCALE)

__device__ __forceinline__ float softplus_fast(float x) {
  return fmaxf(x, 0.f) + __logf(1.f + __expf(-fabsf(x)));
}
__device__ __forceinline__ float softplus_ref(float x) {
  return fmaxf(x, 0.f) + log1pf(expf(-fabsf(x)));
}
__device__ __forceinline__ float wredsum(float x) {
  #pragma unroll
  for (int o = 32; o; o >>= 1) x += __shfl_xor(x, o, 64);
  return x;
}
__device__ __forceinline__ float wredmax(float x) {
  #pragma unroll
  for (int o = 32; o; o >>= 1) x = fmaxf(x, __shfl_xor(x, o, 64));
  return x;
}
__device__ __forceinline__ void global_load_lds16(const void* g, void* l) {
  __builtin_amdgcn_global_load_lds(
      (const __attribute__((address_space(1))) uint32_t*)g,
      (__attribute__((address_space(3))) uint32_t*)l, 16, 0, 0);
}

// OCP e4m3fn encode, x in [0, 448], RNE. Denormal path: value = k*2^-9.
__device__ __forceinline__ uint32_t enc_e4m3(float x) {
  if (x < 0.015625f) return (uint32_t)__float2int_rn(x * 512.0f);
  uint32_t u = __float_as_uint(x);
  u += 0x7FFFFu + ((u >> 20) & 1u);          // RNE to 3-bit mantissa
  return (((u >> 23) - 120u) << 3) | ((u >> 20) & 7u);
}

// ---------------- prep_small ----------------
__global__ __launch_bounds__(256) void prep_small(
    const float* __restrict__ lz, const float* __restrict__ lw,
    const float* __restrict__ gamma, const float* __restrict__ delta,
    const float* __restrict__ pks, const float* __restrict__ Lp,
    float* __restrict__ consts, float* __restrict__ a_tab, float* __restrict__ b_tab,
    float* __restrict__ g_tab, float* __restrict__ d_tab,
    uint32_t* __restrict__ hist, float* __restrict__ out)
{
  int n = blockIdx.x * blockDim.x + threadIdx.x;
  float Lv = softplus_ref(Lp[0]);
  if (n == 0) out[0] = 0.f;
  if (n < NLAYERS*256) hist[n] = 0u;
  if (n < N1) {
    float z0 = lz[n*3], z1 = lz[n*3+1], z2 = lz[n*3+2];
    float m = fmaxf(z0, fmaxf(z1, z2));
    float e0 = expf(z0-m), e1 = expf(z1-m), e2 = expf(z2-m);
    float inv = 1.f/(e0+e1+e2);
    a_tab[0*N1+n] = e0*inv*Lv; a_tab[1*N1+n] = e1*inv*Lv; a_tab[2*N1+n] = e2*inv*Lv;
    float w0 = lw[n*3], w1 = lw[n*3+1], w2 = lw[n*3+2];
    m = fmaxf(w0, fmaxf(w1, w2));
    e0 = expf(w0-m); e1 = expf(w1-m); e2 = expf(w2-m);
    inv = 1.f/(e0+e1+e2);
    b_tab[0*N2+n] = e0*inv+EPSV; b_tab[1*N2+n] = e1*inv+EPSV; b_tab[2*N2+n] = e2*inv+EPSV;
    #pragma unroll
    for (int k = 0; k < 3; ++k) {
      g_tab[k*N1+n] = gamma[n*3+k];
      d_tab[k*N2+n] = delta[n*3+k];
    }
  }
  if (n < NLAYERS) {
    float p[KKC+1]; float m = -1e30f;
    for (int k = 0; k <= KKC; ++k) { p[k] = pks[n*(KKC+1)+k]; m = fmaxf(m, p[k]); }
    float s = 0.f;
    for (int k = 0; k <= KKC; ++k) { p[k] = expf(p[k]-m); s += p[k]; }
    float inv = 1.f/s;
    for (int k = 0; k <= KKC; ++k) consts[8 + n*(KKC+1) + k] = p[k]*inv;
    consts[n] = p[0]*inv + EPSV*(1.f - p[0]*inv);  // c = p0 + EPS*(1-p0)
  }
}

// ---------------- edge binning (R9, unchanged) ----------------
#define EPB 2048

__global__ __launch_bounds__(256) void edge_hist(
    const int* __restrict__ is_, const int* __restrict__ js_,
    uint32_t* __restrict__ hist, int E)
{
  __shared__ uint32_t h[256];
  const int lay = blockIdx.y;
  const int t = threadIdx.x;
  h[t] = 0u;
  __syncthreads();
  const int e0 = blockIdx.x * EPB;
  const int e1 = min(e0 + EPB, E);
  for (int e = e0 + t; e < e1; e += 256) {
    int i = is_[(size_t)lay*E + e], j = js_[(size_t)lay*E + e];
    atomicAdd(&h[(i>>8)*16 + (j>>8)], 1u);
  }
  __syncthreads();
  if (h[t]) atomicAdd(&hist[lay*256 + t], h[t]);
}

__global__ __launch_bounds__(256) void edge_scan(
    const uint32_t* __restrict__ hist, uint32_t* __restrict__ off,
    uint32_t* __restrict__ cursor)
{
  __shared__ uint32_t sa[768], sb[768];
  const int t = threadIdx.x;
  for (int i = t; i < 768; i += 256) sa[i] = hist[i];
  __syncthreads();
  uint32_t* src = sa; uint32_t* dst = sb;
  for (int s = 1; s < 768; s <<= 1) {
    for (int i = t; i < 768; i += 256) dst[i] = src[i] + (i >= s ? src[i-s] : 0u);
    __syncthreads();
    uint32_t* tmp = src; src = dst; dst = tmp;
  }
  for (int i = t; i < 768; i += 256) {
    uint32_t ex = i ? src[i-1] : 0u;
    off[i] = ex; cursor[i] = ex;
  }
  if (t == 0) off[768] = src[767];
}

__global__ __launch_bounds__(256) void edge_scatter(
    const int* __restrict__ is_, const int* __restrict__ js_,
    uint32_t* __restrict__ cursor, uint16_t* __restrict__ ebuf, int E)
{
  __shared__ uint32_t h[256];
  __shared__ uint32_t basev[256];
  const int lay = blockIdx.y;
  const int t = threadIdx.x;
  h[t] = 0u;
  __syncthreads();
  const int e0 = blockIdx.x * EPB;
  const int e1 = min(e0 + EPB, E);
  for (int e = e0 + t; e < e1; e += 256) {
    int i = is_[(size_t)lay*E + e], j = js_[(size_t)lay*E + e];
    atomicAdd(&h[(i>>8)*16 + (j>>8)], 1u);
  }
  __syncthreads();
  basev[t] = h[t] ? atomicAdd(&cursor[lay*256 + t], h[t]) : 0u;
  h[t] = 0u;
  __syncthreads();
  for (int e = e0 + t; e < e1; e += 256) {
    int i = is_[(size_t)lay*E + e], j = js_[(size_t)lay*E + e];
    int b = (i>>8)*16 + (j>>8);
    uint32_t r = atomicAdd(&h[b], 1u);
    ebuf[basev[b] + r] = (uint16_t)(((i & 255) << 8) | (j & 255));
  }
}

// ---------------- prep_rows: wave-per-row softmax (+pyramid), fp8 output ----------------
// grid (N/4, NLAYERS, 2). Lane l holds elems [l*16, l*16+16). Output row = 1024 fp8 bytes.
__global__ __launch_bounds__(256) void prep_rows(
    const float* __restrict__ us, const float* __restrict__ vs,
    uint8_t* __restrict__ zt8, uint8_t* __restrict__ wt8, size_t lstride,
    const float* __restrict__ consts, int layer0)
{
  const int t = threadIdx.x, w = t >> 6, l = t & 63;
  const int n = blockIdx.x*4 + w;
  const int layer = layer0 + blockIdx.y;
  const int zmode = (blockIdx.z == 0);
  const float* src = (zmode ? us : vs) + ((size_t)layer*N1 + n)*DD + l*16;
  uint8_t* dst = (zmode ? zt8 : wt8) + (size_t)blockIdx.y*lstride + (size_t)n*1024 + l*16;

  float e[16];
  {
    const float4* s4 = (const float4*)src;
    float4 u0 = s4[0], u1 = s4[1], u2 = s4[2], u3 = s4[3];
    e[0]=u0.x; e[1]=u0.y; e[2]=u0.z; e[3]=u0.w;
    e[4]=u1.x; e[5]=u1.y; e[6]=u1.z; e[7]=u1.w;
    e[8]=u2.x; e[9]=u2.y; e[10]=u2.z; e[11]=u2.w;
    e[12]=u3.x; e[13]=u3.y; e[14]=u3.z; e[15]=u3.w;
  }
  float mx = e[0];
  #pragma unroll
  for (int i = 1; i < 16; ++i) mx = fmaxf(mx, e[i]);
  mx = wredmax(mx);
  float s = 0.f;
  #pragma unroll
  for (int i = 0; i < 16; ++i) { e[i] = __expf(e[i]-mx); s += e[i]; }
  s = wredsum(s);
  float inv = 1.f/s;
  #pragma unroll
  for (int i = 0; i < 16; ++i) e[i] *= inv;

  uint32_t b4[4] = {0u, 0u, 0u, 0u};
  if (!zmode) {
    #pragma unroll
    for (int i = 0; i < 16; ++i)
      b4[i>>2] |= enc_e4m3(e[i]*WSCALE) << ((i&3)*8);
    *(uint4*)dst = *(uint4*)b4;
    return;
  }
  float s1[8], s2[4], s3[2], s4v;
  #pragma unroll
  for (int i = 0; i < 8; ++i) s1[i] = e[2*i] + e[2*i+1];
  #pragma unroll
  for (int i = 0; i < 4; ++i) s2[i] = s1[2*i] + s1[2*i+1];
  s3[0] = s2[0]+s2[1]; s3[1] = s2[2]+s2[3];
  s4v = s3[0]+s3[1];
  float s5 = s4v + __shfl_xor(s4v, 1, 64);
  float s6 = s5  + __shfl_xor(s5, 2, 64);
  float s7 = s6  + __shfl_xor(s6, 4, 64);
  float s8 = s7  + __shfl_xor(s7, 8, 64);
  float s9 = s8  + __shfl_xor(s8, 16, 64);
  const float* pk = consts + 8 + layer*(KKC+1);
  const float base = pk[4]*s4v + pk[5]*s5 + pk[6]*s6 + pk[7]*s7 + pk[8]*s8 + pk[9]*s9;
  const float p1 = pk[1], p2 = pk[2], p3 = pk[3], p10 = pk[10];
  #pragma unroll
  for (int i = 0; i < 16; ++i) {
    float v = p10*e[i] + p1*s1[i>>1] + p2*s2[i>>2] + p3*s3[i>>3] + base;
    b4[i>>2] |= enc_e4m3(v*ZSCALE) << ((i&3)*8);
  }
  *(uint4*)dst = *(uint4*)b4;
}

// ---------------- 256x256 fp8 GEMM: 4-phase single-barrier + fused epilogue ----------------
// 8 waves (2Mx4N), wave tile 128x64. BK=64 fp8 => tile stage 32KB; FOUR bufs (128KB).
// Buf layout: A 16KB then B 16KB; region = 128 lines x 128B, line L holds rows 2L,2L+1
// (64B each); 16B granules XOR-swizzled g^(L&7) (pre-swizzled global source; b64 reads
// land 2-way/bank = free). Distance-2 staging, vmcnt(4) once per tile (induction: in-flight
// at P4(u) = tile u+2's 4 loads; retires exactly tile u+1). vmcnt(0) only at u=14.
__global__ __launch_bounds__(512, 2) void gemm_fused(
    const uint8_t* __restrict__ Az8, size_t zls,
    const uint8_t* __restrict__ Bw8, size_t wls,
    const float* __restrict__ a_tab, const float* __restrict__ b_tab,
    const float* __restrict__ g_tab, const float* __restrict__ d_tab,
    const float* __restrict__ consts, int layer0,
    const uint32_t* __restrict__ eoff, const uint16_t* __restrict__ ebuf,
    float* __restrict__ out)
{
  extern __shared__ char lds[];                // 4 x 32KB
  const int t = threadIdx.x;
  const int w = t >> 6, l = t & 63;
  const int wm = w >> 2, wn = w & 3;
  const int fr = l & 15, fq = l >> 4;

  // T1: bijective XCD swizzle (768 blocks % 8 == 0)
  const int nbx = gridDim.x, nby = gridDim.y;
  int lid = blockIdx.x + nbx*(blockIdx.y + nby*blockIdx.z);
  const int nblk = nbx*nby*gridDim.z;
  const int cpx = nblk >> 3;
  int nid = (lid & 7)*cpx + (lid >> 3);
  const int bz = nid / (nbx*nby);
  const int rem = nid % (nbx*nby);
  const int bi = rem % nbx, bj = rem / nbx;

  const int i0 = bi*256, j0 = bj*256;
  const int layer = layer0 + bz;
  Az8 += (size_t)bz*zls + (size_t)i0*1024;
  Bw8 += (size_t)bz*wls + (size_t)j0*1024;

  f32x4 acc[8][4];
  f32x4 zero = {0.f, 0.f, 0.f, 0.f};
  #pragma unroll
  for (int m = 0; m < 8; ++m)
    #pragma unroll
    for (int nn = 0; nn < 4; ++nn) acc[m][nn] = zero;

  // stage-side per-lane source offset (within a 16-row chunk)
  const int go = (l & 7) ^ (l >> 3);           // orig granule for this dest slot
  const size_t s_off = (size_t)((l >> 3)*2 + (go >> 2))*1024 + (size_t)(go & 3)*16;
  // read-side per-lane byte offsets, kb16 = kc*2 + (fq>>1)
  int aKc[2];
  #pragma unroll
  for (int kc = 0; kc < 2; ++kc)
    aKc[kc] = (fr>>1)*128 + ((((fr&1)<<2) + kc*2 + (fq>>1)) ^ (fr>>1))*16 + (fq&1)*8;

  long ar[8], br[4];                           // [i][kc], [j][kc]

#define STG_A(tile) do { \
    char* _d = lds + ((tile)&3)*32768 + w*2048; \
    const uint8_t* _s = Az8 + (size_t)(w*32)*1024 + (size_t)(tile)*64 + s_off; \
    global_load_lds16(_s, _d); \
    global_load_lds16(_s + (size_t)16*1024, _d + 1024); \
  } while (0)
#define STG_B(tile) do { \
    char* _d = lds + ((tile)&3)*32768 + 16384 + w*2048; \
    const uint8_t* _s = Bw8 + (size_t)(w*32)*1024 + (size_t)(tile)*64 + s_off; \
    global_load_lds16(_s, _d); \
    global_load_lds16(_s + (size_t)16*1024, _d + 1024); \
  } while (0)
#define LDA(bufb, mq) do { \
    const char* _b = lds + (bufb) + wm*8192; \
    _Pragma("unroll") for (int i = 0; i < 4; ++i) \
    _Pragma("unroll") for (int kc = 0; kc < 2; ++kc) \
      ar[i*2+kc] = *(const long*)(_b + ((mq)*4+i)*1024 + aKc[kc]); \
  } while (0)
#define LDB(bufb, nq) do { \
    const char* _b = lds + (bufb) + 16384 + wn*4096; \
    _Pragma("unroll") for (int j = 0; j < 2; ++j) \
    _Pragma("unroll") for (int kc = 0; kc < 2; ++kc) \
      br[j*2+kc] = *(const long*)(_b + ((nq)*2+j)*1024 + aKc[kc]); \
  } while (0)
#define MM(mq, nq) do { \
    _Pragma("unroll") for (int kc = 0; kc < 2; ++kc) \
    _Pragma("unroll") for (int i = 0; i < 4; ++i) \
    _Pragma("unroll") for (int j = 0; j < 2; ++j) \
      acc[(mq)*4+i][(nq)*2+j] = __builtin_amdgcn_mfma_f32_16x16x32_fp8_fp8( \
          ar[i*2+kc], br[j*2+kc], acc[(mq)*4+i][(nq)*2+j], 0, 0, 0); \
  } while (0)
#define BAR() asm volatile("s_barrier" ::: "memory")
#define PRIO_MM(mq, nq) do { \
    __builtin_amdgcn_s_setprio(1); MM(mq, nq); __builtin_amdgcn_s_setprio(0); } while (0)

  // prologue: stage tiles 0,1; retire tile0 (keep tile1's 4 in flight)
  STG_A(0); STG_B(0); STG_A(1); STG_B(1);
  asm volatile("s_waitcnt vmcnt(4)" ::: "memory");
  BAR();

  #pragma unroll 4
  for (int u = 0; u < 16; ++u) {
    const int cb = (u & 3)*32768;
    // P1
    LDA(cb, 0); LDB(cb, 0);
    if (u < 14) STG_A(u+2);
    BAR(); PRIO_MM(0, 0);
    // P2
    LDB(cb, 1);
    if (u < 14) STG_B(u+2);
    BAR(); PRIO_MM(0, 1);
    // P3
    LDA(cb, 1);
    BAR(); PRIO_MM(1, 0);
    // P4
    if (u < 14)       asm volatile("s_waitcnt vmcnt(4)" ::: "memory");
    else if (u == 14) asm volatile("s_waitcnt vmcnt(0)" ::: "memory");
    BAR(); PRIO_MM(1, 1);
  }
#undef STG_A
#undef STG_B
#undef LDA
#undef LDB
#undef MM
#undef BAR
#undef PRIO_MM

  // ---- epilogue: stage C (bf16, scaled + cc) into LDS 256x512B; dense + sparse sums ----
  const float cc = consts[layer];
  {
    char* cbase = lds + wm*65536 + fq*2048 + wn*128 + fr*2;
    #pragma unroll
    for (int m = 0; m < 8; ++m)
      #pragma unroll
      for (int nn = 0; nn < 4; ++nn)
        #pragma unroll
        for (int r = 0; r < 4; ++r)
          *(bf16_t*)(cbase + m*8192 + r*512 + nn*32) =
              (bf16_t)(acc[m][nn][r]*INVSCALE + cc);
  }
  __syncthreads();

  const float* at = a_tab + layer*N1;
  const float* bt = b_tab + layer*N2;
  const float* gt = g_tab + layer*N1;
  const float* dt = d_tab + layer*N2;
  float dsum = 0.f;
  #pragma unroll 4
  for (int i = 0; i < 16; ++i) {
    const int id = t + i*512;
    const int row = id >> 5, g = id & 31;
    bf16x8 v = *(const bf16x8*)(lds + row*512 + g*16);
    const int grow = i0 + row, gcol = j0 + g*8;
    const float av = at[grow], gv = gt[grow];
    float4 b0 = *(const float4*)(bt + gcol), b1 = *(const float4*)(bt + gcol + 4);
    float4 d0 = *(const float4*)(dt + gcol), d1 = *(const float4*)(dt + gcol + 4);
    float bb[8] = {b0.x,b0.y,b0.z,b0.w,b1.x,b1.y,b1.z,b1.w};
    float dd[8] = {d0.x,d0.y,d0.z,d0.w,d1.x,d1.y,d1.z,d1.w};
    #pragma unroll
    for (int e2 = 0; e2 < 8; ++e2) {
      float x = av*bb[e2]*(float)v[e2] + gv + dd[e2];
      float sp = softplus_fast(x);
      dsum += (grow != gcol + e2) ? sp : 0.f;
    }
  }
  const int bin = bz*256 + bi*16 + bj;
  const uint32_t e0 = eoff[bin], e1 = eoff[bin+1];
  float ssum = 0.f;
  for (uint32_t e = e0 + (uint32_t)t; e < e1; e += 512u) {
    const int pk2 = ebuf[e];
    const int li = pk2 >> 8, lj = pk2 & 255;
    float dc = (float)*(const bf16_t*)(lds + li*512 + lj*2);
    ssum += at[i0+li]*bt[j0+lj]*dc + gt[i0+li] + dt[j0+lj];
  }
  float tot = wredsum(ssum - dsum);
  __syncthreads();
  if (l == 0) ((float*)lds)[w] = tot;
  __syncthreads();
  if (t == 0) {
    const float* r = (const float*)lds;
    float s = 0.f;
    #pragma unroll
    for (int i = 0; i < 8; ++i) s += r[i];
    atomicAdd(out, s);   // ll += z_pdist2 - z_pdist1
  }
}

extern "C" void kernel_launch(void* const* d_in, const int* in_sizes, int n_in,
                              void* d_out, int out_size, void* d_ws, size_t ws_size,
                              hipStream_t stream) {
  const float* us    = (const float*)d_in[0];
  const float* vs    = (const float*)d_in[1];
  const float* gamma = (const float*)d_in[2];
  const float* delta = (const float*)d_in[3];
  const float* lz    = (const float*)d_in[4];
  const float* lw    = (const float*)d_in[5];
  const float* pks   = (const float*)d_in[6];
  const float* Lp    = (const float*)d_in[7];
  const int*   sis   = (const int*)d_in[8];
  const int*   sjs   = (const int*)d_in[9];
  float* out = (float*)d_out;
  char*  ws  = (char*)d_ws;
  const int E = in_sizes[8] / NLAYERS;

  size_t p = 0;
  float* consts = (float*)(ws + p); p += 1024;
  float* a_tab  = (float*)(ws + p); p += (size_t)NLAYERS*N1*4;
  float* b_tab  = (float*)(ws + p); p += (size_t)NLAYERS*N2*4;
  float* g_tab  = (float*)(ws + p); p += (size_t)NLAYERS*N1*4;
  float* d_tab  = (float*)(ws + p); p += (size_t)NLAYERS*N2*4;
  uint32_t* hist   = (uint32_t*)(ws + p); p += 1024*4;
  uint32_t* eoff   = (uint32_t*)(ws + p); p += 1024*4;
  uint32_t* cursor = (uint32_t*)(ws + p); p += 1024*4;
  uint16_t* ebuf   = (uint16_t*)(ws + p); p += (size_t)NLAYERS*E*2;
  p = (p + 4095) & ~(size_t)4095;
  uint8_t* zt8 = (uint8_t*)(ws + p); p += (size_t)NLAYERS*N1*1024;
  uint8_t* wt8 = (uint8_t*)(ws + p); p += (size_t)NLAYERS*N2*1024;
  if (ws_size < p) return;
  const size_t ZLS = (size_t)N1*1024;
  const size_t LDSB = 131072;
  const int nebl = (E + EPB - 1) / EPB;

  prep_small<<<(N1+255)/256, 256, 0, stream>>>(lz, lw, gamma, delta, pks, Lp,
                                               consts, a_tab, b_tab, g_tab, d_tab,
                                               hist, out);
  edge_hist<<<dim3(nebl, NLAYERS), 256, 0, stream>>>(sis, sjs, hist, E);
  edge_scan<<<1, 256, 0, stream>>>(hist, eoff, cursor);
  edge_scatter<<<dim3(nebl, NLAYERS), 256, 0, stream>>>(sis, sjs, cursor, ebuf, E);
  prep_rows<<<dim3(N1/4, NLAYERS, 2), 256, 0, stream>>>(us, vs, zt8, wt8, ZLS, consts, 0);
  gemm_fused<<<dim3(16,16,NLAYERS), 512, LDSB, stream>>>(
      zt8, ZLS, wt8, ZLS, a_tab, b_tab, g_tab, d_tab, consts, 0, eoff, ebuf, out);
}

// Round 11
// 151.824 us; speedup vs baseline: 3.8396x; 1.0209x over previous
//
#include <hip/hip_runtime.h>
#include <hip/hip_bf16.h>
#include <stdint.h>

#define EPSV 1e-6f
#define N1 4096
#define N2 4096
#define DD 1024
#define NLAYERS 3
#define KKC 10

typedef __bf16 bf16_t;
typedef __bf16 bf16x8 __attribute__((ext_vector_type(8)));
typedef float f32x4 __attribute__((ext_vector_type(4)));
typedef long longx2 __attribute__((ext_vector_type(2)));

#define ZSCALE 256.0f
#define WSCALE 64.0f
#define INVSCALE 6.103515625e-05f   // 1/(ZSCALE*WSCALE)

__device__ __forceinline__ float softplus_fast(float x) {
  return fmaxf(x, 0.f) + __logf(1.f + __expf(-fabsf(x)));
}
__device__ __forceinline__ float softplus_ref(float x) {
  return fmaxf(x, 0.f) + log1pf(expf(-fabsf(x)));
}
__device__ __forceinline__ float wredsum(float x) {
  #pragma unroll
  for (int o = 32; o; o >>= 1) x += __shfl_xor(x, o, 64);
  return x;
}
__device__ __forceinline__ float wredmax(float x) {
  #pragma unroll
  for (int o = 32; o; o >>= 1) x = fmaxf(x, __shfl_xor(x, o, 64));
  return x;
}
__device__ __forceinline__ void global_load_lds16(const void* g, void* l) {
  __builtin_amdgcn_global_load_lds(
      (const __attribute__((address_space(1))) uint32_t*)g,
      (__attribute__((address_space(3))) uint32_t*)l, 16, 0, 0);
}

// OCP e4m3fn encode, x in [0, 448], RNE. Denormal path: value = k*2^-9.
__device__ __forceinline__ uint32_t enc_e4m3(float x) {
  if (x < 0.015625f) return (uint32_t)__float2int_rn(x * 512.0f);
  uint32_t u = __float_as_uint(x);
  u += 0x7FFFFu + ((u >> 20) & 1u);          // RNE to 3-bit mantissa
  return (((u >> 23) - 120u) << 3) | ((u >> 20) & 7u);
}

// ---------------- prep_small ----------------
__global__ __launch_bounds__(256) void prep_small(
    const float* __restrict__ lz, const float* __restrict__ lw,
    const float* __restrict__ gamma, const float* __restrict__ delta,
    const float* __restrict__ pks, const float* __restrict__ Lp,
    float* __restrict__ consts, float* __restrict__ a_tab, float* __restrict__ b_tab,
    float* __restrict__ g_tab, float* __restrict__ d_tab,
    uint32_t* __restrict__ hist, float* __restrict__ out)
{
  int n = blockIdx.x * blockDim.x + threadIdx.x;
  float Lv = softplus_ref(Lp[0]);
  if (n == 0) out[0] = 0.f;
  if (n < NLAYERS*256) hist[n] = 0u;
  if (n < N1) {
    float z0 = lz[n*3], z1 = lz[n*3+1], z2 = lz[n*3+2];
    float m = fmaxf(z0, fmaxf(z1, z2));
    float e0 = expf(z0-m), e1 = expf(z1-m), e2 = expf(z2-m);
    float inv = 1.f/(e0+e1+e2);
    a_tab[0*N1+n] = e0*inv*Lv; a_tab[1*N1+n] = e1*inv*Lv; a_tab[2*N1+n] = e2*inv*Lv;
    float w0 = lw[n*3], w1 = lw[n*3+1], w2 = lw[n*3+2];
    m = fmaxf(w0, fmaxf(w1, w2));
    e0 = expf(w0-m); e1 = expf(w1-m); e2 = expf(w2-m);
    inv = 1.f/(e0+e1+e2);
    b_tab[0*N2+n] = e0*inv+EPSV; b_tab[1*N2+n] = e1*inv+EPSV; b_tab[2*N2+n] = e2*inv+EPSV;
    #pragma unroll
    for (int k = 0; k < 3; ++k) {
      g_tab[k*N1+n] = gamma[n*3+k];
      d_tab[k*N2+n] = delta[n*3+k];
    }
  }
  if (n < NLAYERS) {
    float p[KKC+1]; float m = -1e30f;
    for (int k = 0; k <= KKC; ++k) { p[k] = pks[n*(KKC+1)+k]; m = fmaxf(m, p[k]); }
    float s = 0.f;
    for (int k = 0; k <= KKC; ++k) { p[k] = expf(p[k]-m); s += p[k]; }
    float inv = 1.f/s;
    for (int k = 0; k <= KKC; ++k) consts[8 + n*(KKC+1) + k] = p[k]*inv;
    consts[n] = p[0]*inv + EPSV*(1.f - p[0]*inv);  // c = p0 + EPS*(1-p0)
  }
}

// ---------------- edge binning (R9, unchanged) ----------------
#define EPB 2048

__global__ __launch_bounds__(256) void edge_hist(
    const int* __restrict__ is_, const int* __restrict__ js_,
    uint32_t* __restrict__ hist, int E)
{
  __shared__ uint32_t h[256];
  const int lay = blockIdx.y;
  const int t = threadIdx.x;
  h[t] = 0u;
  __syncthreads();
  const int e0 = blockIdx.x * EPB;
  const int e1 = min(e0 + EPB, E);
  for (int e = e0 + t; e < e1; e += 256) {
    int i = is_[(size_t)lay*E + e], j = js_[(size_t)lay*E + e];
    atomicAdd(&h[(i>>8)*16 + (j>>8)], 1u);
  }
  __syncthreads();
  if (h[t]) atomicAdd(&hist[lay*256 + t], h[t]);
}

__global__ __launch_bounds__(256) void edge_scan(
    const uint32_t* __restrict__ hist, uint32_t* __restrict__ off,
    uint32_t* __restrict__ cursor)
{
  __shared__ uint32_t sa[768], sb[768];
  const int t = threadIdx.x;
  for (int i = t; i < 768; i += 256) sa[i] = hist[i];
  __syncthreads();
  uint32_t* src = sa; uint32_t* dst = sb;
  for (int s = 1; s < 768; s <<= 1) {
    for (int i = t; i < 768; i += 256) dst[i] = src[i] + (i >= s ? src[i-s] : 0u);
    __syncthreads();
    uint32_t* tmp = src; src = dst; dst = tmp;
  }
  for (int i = t; i < 768; i += 256) {
    uint32_t ex = i ? src[i-1] : 0u;
    off[i] = ex; cursor[i] = ex;
  }
  if (t == 0) off[768] = src[767];
}

__global__ __launch_bounds__(256) void edge_scatter(
    const int* __restrict__ is_, const int* __restrict__ js_,
    uint32_t* __restrict__ cursor, uint16_t* __restrict__ ebuf, int E)
{
  __shared__ uint32_t h[256];
  __shared__ uint32_t basev[256];
  const int lay = blockIdx.y;
  const int t = threadIdx.x;
  h[t] = 0u;
  __syncthreads();
  const int e0 = blockIdx.x * EPB;
  const int e1 = min(e0 + EPB, E);
  for (int e = e0 + t; e < e1; e += 256) {
    int i = is_[(size_t)lay*E + e], j = js_[(size_t)lay*E + e];
    atomicAdd(&h[(i>>8)*16 + (j>>8)], 1u);
  }
  __syncthreads();
  basev[t] = h[t] ? atomicAdd(&cursor[lay*256 + t], h[t]) : 0u;
  h[t] = 0u;
  __syncthreads();
  for (int e = e0 + t; e < e1; e += 256) {
    int i = is_[(size_t)lay*E + e], j = js_[(size_t)lay*E + e];
    int b = (i>>8)*16 + (j>>8);
    uint32_t r = atomicAdd(&h[b], 1u);
    ebuf[basev[b] + r] = (uint16_t)(((i & 255) << 8) | (j & 255));
  }
}

// ---------------- prep_rows: wave-per-row softmax (+pyramid), fp8 PERMUTED output ----------------
// Within each 64-byte k-block, bytes stored at p = fq*16 + kc*8 + b for source
// k = kc*32 + fq*8 + b  =>  a lane's (kc0,kc1) MFMA operands are contiguous 16B.
// Lane l holds k in [16l,16l+16) = two 8B chunks at p0 and p0+16.
__global__ __launch_bounds__(256) void prep_rows(
    const float* __restrict__ us, const float* __restrict__ vs,
    uint8_t* __restrict__ zt8, uint8_t* __restrict__ wt8, size_t lstride,
    const float* __restrict__ consts, int layer0)
{
  const int t = threadIdx.x, w = t >> 6, l = t & 63;
  const int n = blockIdx.x*4 + w;
  const int layer = layer0 + blockIdx.y;
  const int zmode = (blockIdx.z == 0);
  const float* src = (zmode ? us : vs) + ((size_t)layer*N1 + n)*DD + l*16;
  uint8_t* drow = (zmode ? zt8 : wt8) + (size_t)blockIdx.y*lstride + (size_t)n*1024;
  const int p0 = (l>>2)*64 + ((l&1)*2)*16 + ((l&3)>>1)*8;   // t6*64 + fq_l*16 + kc_l*8

  float e[16];
  {
    const float4* s4 = (const float4*)src;
    float4 u0 = s4[0], u1 = s4[1], u2 = s4[2], u3 = s4[3];
    e[0]=u0.x; e[1]=u0.y; e[2]=u0.z; e[3]=u0.w;
    e[4]=u1.x; e[5]=u1.y; e[6]=u1.z; e[7]=u1.w;
    e[8]=u2.x; e[9]=u2.y; e[10]=u2.z; e[11]=u2.w;
    e[12]=u3.x; e[13]=u3.y; e[14]=u3.z; e[15]=u3.w;
  }
  float mx = e[0];
  #pragma unroll
  for (int i = 1; i < 16; ++i) mx = fmaxf(mx, e[i]);
  mx = wredmax(mx);
  float s = 0.f;
  #pragma unroll
  for (int i = 0; i < 16; ++i) { e[i] = __expf(e[i]-mx); s += e[i]; }
  s = wredsum(s);
  float inv = 1.f/s;
  #pragma unroll
  for (int i = 0; i < 16; ++i) e[i] *= inv;

  uint32_t b4[4] = {0u, 0u, 0u, 0u};
  if (!zmode) {
    #pragma unroll
    for (int i = 0; i < 16; ++i)
      b4[i>>2] |= enc_e4m3(e[i]*WSCALE) << ((i&3)*8);
  } else {
    float s1[8], s2[4], s3[2], s4v;
    #pragma unroll
    for (int i = 0; i < 8; ++i) s1[i] = e[2*i] + e[2*i+1];
    #pragma unroll
    for (int i = 0; i < 4; ++i) s2[i] = s1[2*i] + s1[2*i+1];
    s3[0] = s2[0]+s2[1]; s3[1] = s2[2]+s2[3];
    s4v = s3[0]+s3[1];
    float s5 = s4v + __shfl_xor(s4v, 1, 64);
    float s6 = s5  + __shfl_xor(s5, 2, 64);
    float s7 = s6  + __shfl_xor(s6, 4, 64);
    float s8 = s7  + __shfl_xor(s7, 8, 64);
    float s9 = s8  + __shfl_xor(s8, 16, 64);
    const float* pk = consts + 8 + layer*(KKC+1);
    const float base = pk[4]*s4v + pk[5]*s5 + pk[6]*s6 + pk[7]*s7 + pk[8]*s8 + pk[9]*s9;
    const float p1 = pk[1], p2 = pk[2], p3 = pk[3], p10 = pk[10];
    #pragma unroll
    for (int i = 0; i < 16; ++i) {
      float v = p10*e[i] + p1*s1[i>>1] + p2*s2[i>>2] + p3*s3[i>>3] + base;
      b4[i>>2] |= enc_e4m3(v*ZSCALE) << ((i&3)*8);
    }
  }
  uint64_t u0 = (uint64_t)b4[0] | ((uint64_t)b4[1] << 32);
  uint64_t u1 = (uint64_t)b4[2] | ((uint64_t)b4[3] << 32);
  *(uint64_t*)(drow + p0)      = u0;
  *(uint64_t*)(drow + p0 + 16) = u1;
}

// ---------------- 256x256 fp8 GEMM: 4-phase single-barrier, b128 reads + fused epilogue ----------------
// LDS image per buf (32KB): A 16KB then B 16KB; 128-byte line L = rows {2L,2L+1},
// slot s (16B) holds go = s^(L&7), go = (row&1)*4 + quarter; quarter fq of the
// permuted row = lane fq's {kc0|kc1} 16B. Reads: ds_read_b128, 8-lane groups hit
// all 8 slots (R9-verified conflict-free). Distance-2 staging, vmcnt(4)/tile.
__global__ __launch_bounds__(512, 2) void gemm_fused(
    const uint8_t* __restrict__ Az8, size_t zls,
    const uint8_t* __restrict__ Bw8, size_t wls,
    const float* __restrict__ a_tab, const float* __restrict__ b_tab,
    const float* __restrict__ g_tab, const float* __restrict__ d_tab,
    const float* __restrict__ consts, int layer0,
    const uint32_t* __restrict__ eoff, const uint16_t* __restrict__ ebuf,
    float* __restrict__ out)
{
  extern __shared__ char lds[];                // 4 x 32KB
  const int t = threadIdx.x;
  const int w = t >> 6, l = t & 63;
  const int wm = w >> 2, wn = w & 3;
  const int fr = l & 15, fq = l >> 4;

  // T1: bijective XCD swizzle (768 blocks % 8 == 0)
  const int nbx = gridDim.x, nby = gridDim.y;
  int lid = blockIdx.x + nbx*(blockIdx.y + nby*blockIdx.z);
  const int nblk = nbx*nby*gridDim.z;
  const int cpx = nblk >> 3;
  int nid = (lid & 7)*cpx + (lid >> 3);
  const int bz = nid / (nbx*nby);
  const int rem = nid % (nbx*nby);
  const int bi = rem % nbx, bj = rem / nbx;

  const int i0 = bi*256, j0 = bj*256;
  const int layer = layer0 + bz;
  Az8 += (size_t)bz*zls + (size_t)i0*1024;
  Bw8 += (size_t)bz*wls + (size_t)j0*1024;

  f32x4 acc[8][4];
  f32x4 zero = {0.f, 0.f, 0.f, 0.f};
  #pragma unroll
  for (int m = 0; m < 8; ++m)
    #pragma unroll
    for (int nn = 0; nn < 4; ++nn) acc[m][nn] = zero;

  // stage-side per-lane source offset (unchanged from R10; involution verified)
  const int go = (l & 7) ^ (l >> 3);
  const size_t s_off = (size_t)((l >> 3)*2 + (go >> 2))*1024 + (size_t)(go & 3)*16;
  // read-side slot offsets (line = fr>>1 within 8-line stripe)
  const int sl = fr >> 1;
  const int slot = (((fr & 1) << 2) + fq) ^ sl;
  const int abase = wm*8192 + sl*128 + slot*16;
  const int bbase = 16384 + wn*4096 + sl*128 + slot*16;

  longx2 ar2[4], br2[4];

#define STG_A(tile) do { \
    char* _d = lds + ((tile)&3)*32768 + w*2048; \
    const uint8_t* _s = Az8 + (size_t)(w*32)*1024 + (size_t)(tile)*64 + s_off; \
    global_load_lds16(_s, _d); \
    global_load_lds16(_s + (size_t)16*1024, _d + 1024); \
  } while (0)
#define STG_B(tile) do { \
    char* _d = lds + ((tile)&3)*32768 + 16384 + w*2048; \
    const uint8_t* _s = Bw8 + (size_t)(w*32)*1024 + (size_t)(tile)*64 + s_off; \
    global_load_lds16(_s, _d); \
    global_load_lds16(_s + (size_t)16*1024, _d + 1024); \
  } while (0)
#define LDA(bufb, mq) do { \
    const char* _b = lds + (bufb) + abase; \
    _Pragma("unroll") for (int i = 0; i < 4; ++i) \
      ar2[i] = *(const longx2*)(_b + ((mq)*4+i)*1024); \
  } while (0)
#define LDB(bufb, nq) do { \
    const char* _b = lds + (bufb) + bbase; \
    _Pragma("unroll") for (int j = 0; j < 2; ++j) \
      br2[(nq)*2+j] = *(const longx2*)(_b + ((nq)*2+j)*1024); \
  } while (0)
#define MM(mq, nq) do { \
    _Pragma("unroll") for (int i = 0; i < 4; ++i) \
    _Pragma("unroll") for (int j = 0; j < 2; ++j) { \
      acc[(mq)*4+i][(nq)*2+j] = __builtin_amdgcn_mfma_f32_16x16x32_fp8_fp8( \
          ar2[i].x, br2[(nq)*2+j].x, acc[(mq)*4+i][(nq)*2+j], 0, 0, 0); \
      acc[(mq)*4+i][(nq)*2+j] = __builtin_amdgcn_mfma_f32_16x16x32_fp8_fp8( \
          ar2[i].y, br2[(nq)*2+j].y, acc[(mq)*4+i][(nq)*2+j], 0, 0, 0); } \
  } while (0)
#define BAR() asm volatile("s_barrier" ::: "memory")
#define PRIO_MM(mq, nq) do { \
    __builtin_amdgcn_s_setprio(1); MM(mq, nq); __builtin_amdgcn_s_setprio(0); } while (0)

  // prologue: stage tiles 0,1; retire tile0 (keep tile1's 4 in flight)
  STG_A(0); STG_B(0); STG_A(1); STG_B(1);
  asm volatile("s_waitcnt vmcnt(4)" ::: "memory");
  BAR();

  #pragma unroll 4
  for (int u = 0; u < 16; ++u) {
    const int cb = (u & 3)*32768;
    // P1
    LDA(cb, 0); LDB(cb, 0);
    if (u < 14) STG_A(u+2);
    BAR(); PRIO_MM(0, 0);
    // P2
    LDB(cb, 1);
    if (u < 14) STG_B(u+2);
    BAR(); PRIO_MM(0, 1);
    // P3
    LDA(cb, 1);
    BAR(); PRIO_MM(1, 0);
    // P4
    if (u < 14)       asm volatile("s_waitcnt vmcnt(4)" ::: "memory");
    else if (u == 14) asm volatile("s_waitcnt vmcnt(0)" ::: "memory");
    BAR(); PRIO_MM(1, 1);
  }
#undef STG_A
#undef STG_B
#undef LDA
#undef LDB
#undef MM
#undef BAR
#undef PRIO_MM

  // ---- epilogue: stage C (bf16, scaled + cc) into LDS 256x512B; dense + sparse sums ----
  const float cc = consts[layer];
  {
    char* cbase = lds + wm*65536 + fq*2048 + wn*128 + fr*2;
    #pragma unroll
    for (int m = 0; m < 8; ++m)
      #pragma unroll
      for (int nn = 0; nn < 4; ++nn)
        #pragma unroll
        for (int r = 0; r < 4; ++r)
          *(bf16_t*)(cbase + m*8192 + r*512 + nn*32) =
              (bf16_t)(acc[m][nn][r]*INVSCALE + cc);
  }
  __syncthreads();

  const float* at = a_tab + layer*N1;
  const float* bt = b_tab + layer*N2;
  const float* gt = g_tab + layer*N1;
  const float* dt = d_tab + layer*N2;
  float dsum = 0.f;
  #pragma unroll 4
  for (int i = 0; i < 16; ++i) {
    const int id = t + i*512;
    const int row = id >> 5, g = id & 31;
    bf16x8 v = *(const bf16x8*)(lds + row*512 + g*16);
    const int grow = i0 + row, gcol = j0 + g*8;
    const float av = at[grow], gv = gt[grow];
    float4 b0 = *(const float4*)(bt + gcol), b1 = *(const float4*)(bt + gcol + 4);
    float4 d0 = *(const float4*)(dt + gcol), d1 = *(const float4*)(dt + gcol + 4);
    float bb[8] = {b0.x,b0.y,b0.z,b0.w,b1.x,b1.y,b1.z,b1.w};
    float dd[8] = {d0.x,d0.y,d0.z,d0.w,d1.x,d1.y,d1.z,d1.w};
    #pragma unroll
    for (int e2 = 0; e2 < 8; ++e2) {
      float x = av*bb[e2]*(float)v[e2] + gv + dd[e2];
      float sp = softplus_fast(x);
      dsum += (grow != gcol + e2) ? sp : 0.f;
    }
  }
  const int bin = bz*256 + bi*16 + bj;
  const uint32_t e0 = eoff[bin], e1 = eoff[bin+1];
  float ssum = 0.f;
  for (uint32_t e = e0 + (uint32_t)t; e < e1; e += 512u) {
    const int pk2 = ebuf[e];
    const int li = pk2 >> 8, lj = pk2 & 255;
    float dc = (float)*(const bf16_t*)(lds + li*512 + lj*2);
    ssum += at[i0+li]*bt[j0+lj]*dc + gt[i0+li] + dt[j0+lj];
  }
  float tot = wredsum(ssum - dsum);
  __syncthreads();
  if (l == 0) ((float*)lds)[w] = tot;
  __syncthreads();
  if (t == 0) {
    const float* r = (const float*)lds;
    float s = 0.f;
    #pragma unroll
    for (int i = 0; i < 8; ++i) s += r[i];
    atomicAdd(out, s);   // ll += z_pdist2 - z_pdist1
  }
}

extern "C" void kernel_launch(void* const* d_in, const int* in_sizes, int n_in,
                              void* d_out, int out_size, void* d_ws, size_t ws_size,
                              hipStream_t stream) {
  const float* us    = (const float*)d_in[0];
  const float* vs    = (const float*)d_in[1];
  const float* gamma = (const float*)d_in[2];
  const float* delta = (const float*)d_in[3];
  const float* lz    = (const float*)d_in[4];
  const float* lw    = (const float*)d_in[5];
  const float* pks   = (const float*)d_in[6];
  const float* Lp    = (const float*)d_in[7];
  const int*   sis   = (const int*)d_in[8];
  const int*   sjs   = (const int*)d_in[9];
  float* out = (float*)d_out;
  char*  ws  = (char*)d_ws;
  const int E = in_sizes[8] / NLAYERS;

  size_t p = 0;
  float* consts = (float*)(ws + p); p += 1024;
  float* a_tab  = (float*)(ws + p); p += (size_t)NLAYERS*N1*4;
  float* b_tab  = (float*)(ws + p); p += (size_t)NLAYERS*N2*4;
  float* g_tab  = (float*)(ws + p); p += (size_t)NLAYERS*N1*4;
  float* d_tab  = (float*)(ws + p); p += (size_t)NLAYERS*N2*4;
  uint32_t* hist   = (uint32_t*)(ws + p); p += 1024*4;
  uint32_t* eoff   = (uint32_t*)(ws + p); p += 1024*4;
  uint32_t* cursor = (uint32_t*)(ws + p); p += 1024*4;
  uint16_t* ebuf   = (uint16_t*)(ws + p); p += (size_t)NLAYERS*E*2;
  p = (p + 4095) & ~(size_t)4095;
  uint8_t* zt8 = (uint8_t*)(ws + p); p += (size_t)NLAYERS*N1*1024;
  uint8_t* wt8 = (uint8_t*)(ws + p); p += (size_t)NLAYERS*N2*1024;
  if (ws_size < p) return;
  const size_t ZLS = (size_t)N1*1024;
  const size_t LDSB = 131072;
  const int nebl = (E + EPB - 1) / EPB;

  prep_small<<<(N1+255)/256, 256, 0, stream>>>(lz, lw, gamma, delta, pks, Lp,
                                               consts, a_tab, b_tab, g_tab, d_tab,
                                               hist, out);
  edge_hist<<<dim3(nebl, NLAYERS), 256, 0, stream>>>(sis, sjs, hist, E);
  edge_scan<<<1, 256, 0, stream>>>(hist, eoff, cursor);
  edge_scatter<<<dim3(nebl, NLAYERS), 256, 0, stream>>>(sis, sjs, cursor, ebuf, E);
  prep_rows<<<dim3(N1/4, NLAYERS, 2), 256, 0, stream>>>(us, vs, zt8, wt8, ZLS, consts, 0);
  gemm_fused<<<dim3(16,16,NLAYERS), 512, LDSB, stream>>>(
      zt8, ZLS, wt8, ZLS, a_tab, b_tab, g_tab, d_tab, consts, 0, eoff, ebuf, out);
}

// Round 12
// 139.889 us; speedup vs baseline: 4.1672x; 1.0853x over previous
//
#include <hip/hip_runtime.h>
#include <hip/hip_bf16.h>
#include <stdint.h>

#define EPSV 1e-6f
#define N1 4096
#define N2 4096
#define DD 1024
#define NLAYERS 3
#define KKC 10

typedef __bf16 bf16_t;
typedef __bf16 bf16x8 __attribute__((ext_vector_type(8)));
typedef float f32x4 __attribute__((ext_vector_type(4)));
typedef long longx2 __attribute__((ext_vector_type(2)));

#define ZSCALE 256.0f
#define WSCALE 64.0f
#define INVSCALE 6.103515625e-05f   // 1/(ZSCALE*WSCALE)

// bins: 32 i-bins (128 rows) x 16 j-bins (256 cols) = 512 per layer, 1536 total
#define NBIN_L 512
#define NBIN_T (NLAYERS*NBIN_L)

__device__ __forceinline__ float softplus_fast(float x) {
  return fmaxf(x, 0.f) + __logf(1.f + __expf(-fabsf(x)));
}
__device__ __forceinline__ float softplus_ref(float x) {
  return fmaxf(x, 0.f) + log1pf(expf(-fabsf(x)));
}
__device__ __forceinline__ float wredsum(float x) {
  #pragma unroll
  for (int o = 32; o; o >>= 1) x += __shfl_xor(x, o, 64);
  return x;
}
__device__ __forceinline__ float wredmax(float x) {
  #pragma unroll
  for (int o = 32; o; o >>= 1) x = fmaxf(x, __shfl_xor(x, o, 64));
  return x;
}
__device__ __forceinline__ void global_load_lds16(const void* g, void* l) {
  __builtin_amdgcn_global_load_lds(
      (const __attribute__((address_space(1))) uint32_t*)g,
      (__attribute__((address_space(3))) uint32_t*)l, 16, 0, 0);
}

// OCP e4m3fn encode, x in [0, 448], RNE. Denormal path: value = k*2^-9.
__device__ __forceinline__ uint32_t enc_e4m3(float x) {
  if (x < 0.015625f) return (uint32_t)__float2int_rn(x * 512.0f);
  uint32_t u = __float_as_uint(x);
  u += 0x7FFFFu + ((u >> 20) & 1u);
  return (((u >> 23) - 120u) << 3) | ((u >> 20) & 7u);
}

// ---------------- prep_small ----------------
__global__ __launch_bounds__(256) void prep_small(
    const float* __restrict__ lz, const float* __restrict__ lw,
    const float* __restrict__ gamma, const float* __restrict__ delta,
    const float* __restrict__ pks, const float* __restrict__ Lp,
    float* __restrict__ consts, float* __restrict__ a_tab, float* __restrict__ b_tab,
    float* __restrict__ g_tab, float* __restrict__ d_tab,
    uint32_t* __restrict__ hist, float* __restrict__ out)
{
  int n = blockIdx.x * blockDim.x + threadIdx.x;
  float Lv = softplus_ref(Lp[0]);
  if (n == 0) out[0] = 0.f;
  if (n < NBIN_T) hist[n] = 0u;
  if (n < N1) {
    float z0 = lz[n*3], z1 = lz[n*3+1], z2 = lz[n*3+2];
    float m = fmaxf(z0, fmaxf(z1, z2));
    float e0 = expf(z0-m), e1 = expf(z1-m), e2 = expf(z2-m);
    float inv = 1.f/(e0+e1+e2);
    a_tab[0*N1+n] = e0*inv*Lv; a_tab[1*N1+n] = e1*inv*Lv; a_tab[2*N1+n] = e2*inv*Lv;
    float w0 = lw[n*3], w1 = lw[n*3+1], w2 = lw[n*3+2];
    m = fmaxf(w0, fmaxf(w1, w2));
    e0 = expf(w0-m); e1 = expf(w1-m); e2 = expf(w2-m);
    inv = 1.f/(e0+e1+e2);
    b_tab[0*N2+n] = e0*inv+EPSV; b_tab[1*N2+n] = e1*inv+EPSV; b_tab[2*N2+n] = e2*inv+EPSV;
    #pragma unroll
    for (int k = 0; k < 3; ++k) {
      g_tab[k*N1+n] = gamma[n*3+k];
      d_tab[k*N2+n] = delta[n*3+k];
    }
  }
  if (n < NLAYERS) {
    float p[KKC+1]; float m = -1e30f;
    for (int k = 0; k <= KKC; ++k) { p[k] = pks[n*(KKC+1)+k]; m = fmaxf(m, p[k]); }
    float s = 0.f;
    for (int k = 0; k <= KKC; ++k) { p[k] = expf(p[k]-m); s += p[k]; }
    float inv = 1.f/s;
    for (int k = 0; k <= KKC; ++k) consts[8 + n*(KKC+1) + k] = p[k]*inv;
    consts[n] = p[0]*inv + EPSV*(1.f - p[0]*inv);
  }
}

// ---------------- edge binning ----------------
#define EPB 2048

__global__ __launch_bounds__(256) void edge_hist(
    const int* __restrict__ is_, const int* __restrict__ js_,
    uint32_t* __restrict__ hist, int E)
{
  __shared__ uint32_t h[NBIN_L];
  const int lay = blockIdx.y;
  const int t = threadIdx.x;
  h[t] = 0u; h[t+256] = 0u;
  __syncthreads();
  const int e0 = blockIdx.x * EPB;
  const int e1 = min(e0 + EPB, E);
  for (int e = e0 + t; e < e1; e += 256) {
    int i = is_[(size_t)lay*E + e], j = js_[(size_t)lay*E + e];
    atomicAdd(&h[(i>>7)*16 + (j>>8)], 1u);
  }
  __syncthreads();
  if (h[t])     atomicAdd(&hist[lay*NBIN_L + t], h[t]);
  if (h[t+256]) atomicAdd(&hist[lay*NBIN_L + t + 256], h[t+256]);
}

__global__ __launch_bounds__(256) void edge_scan(
    const uint32_t* __restrict__ hist, uint32_t* __restrict__ off,
    uint32_t* __restrict__ cursor)
{
  __shared__ uint32_t sa[NBIN_T], sb[NBIN_T];
  const int t = threadIdx.x;
  for (int i = t; i < NBIN_T; i += 256) sa[i] = hist[i];
  __syncthreads();
  uint32_t* src = sa; uint32_t* dst = sb;
  for (int s = 1; s < NBIN_T; s <<= 1) {
    for (int i = t; i < NBIN_T; i += 256) dst[i] = src[i] + (i >= s ? src[i-s] : 0u);
    __syncthreads();
    uint32_t* tmp = src; src = dst; dst = tmp;
  }
  for (int i = t; i < NBIN_T; i += 256) {
    uint32_t ex = i ? src[i-1] : 0u;
    off[i] = ex; cursor[i] = ex;
  }
  if (t == 0) off[NBIN_T] = src[NBIN_T-1];
}

__global__ __launch_bounds__(256) void edge_scatter(
    const int* __restrict__ is_, const int* __restrict__ js_,
    uint32_t* __restrict__ cursor, uint16_t* __restrict__ ebuf, int E)
{
  __shared__ uint32_t h[NBIN_L];
  __shared__ uint32_t basev[NBIN_L];
  const int lay = blockIdx.y;
  const int t = threadIdx.x;
  h[t] = 0u; h[t+256] = 0u;
  __syncthreads();
  const int e0 = blockIdx.x * EPB;
  const int e1 = min(e0 + EPB, E);
  for (int e = e0 + t; e < e1; e += 256) {
    int i = is_[(size_t)lay*E + e], j = js_[(size_t)lay*E + e];
    atomicAdd(&h[(i>>7)*16 + (j>>8)], 1u);
  }
  __syncthreads();
  basev[t]     = h[t]     ? atomicAdd(&cursor[lay*NBIN_L + t], h[t]) : 0u;
  basev[t+256] = h[t+256] ? atomicAdd(&cursor[lay*NBIN_L + t + 256], h[t+256]) : 0u;
  h[t] = 0u; h[t+256] = 0u;
  __syncthreads();
  for (int e = e0 + t; e < e1; e += 256) {
    int i = is_[(size_t)lay*E + e], j = js_[(size_t)lay*E + e];
    int b = (i>>7)*16 + (j>>8);
    uint32_t r = atomicAdd(&h[b], 1u);
    ebuf[basev[b] + r] = (uint16_t)(((i & 127) << 8) | (j & 255));
  }
}

// ---------------- prep_rows: wave-per-row softmax (+pyramid), fp8 PERMUTED output ----------------
__global__ __launch_bounds__(256) void prep_rows(
    const float* __restrict__ us, const float* __restrict__ vs,
    uint8_t* __restrict__ zt8, uint8_t* __restrict__ wt8, size_t lstride,
    const float* __restrict__ consts, int layer0)
{
  const int t = threadIdx.x, w = t >> 6, l = t & 63;
  const int n = blockIdx.x*4 + w;
  const int layer = layer0 + blockIdx.y;
  const int zmode = (blockIdx.z == 0);
  const float* src = (zmode ? us : vs) + ((size_t)layer*N1 + n)*DD + l*16;
  uint8_t* drow = (zmode ? zt8 : wt8) + (size_t)blockIdx.y*lstride + (size_t)n*1024;
  const int p0 = (l>>2)*64 + ((l&1)*2)*16 + ((l&3)>>1)*8;

  float e[16];
  {
    const float4* s4 = (const float4*)src;
    float4 u0 = s4[0], u1 = s4[1], u2 = s4[2], u3 = s4[3];
    e[0]=u0.x; e[1]=u0.y; e[2]=u0.z; e[3]=u0.w;
    e[4]=u1.x; e[5]=u1.y; e[6]=u1.z; e[7]=u1.w;
    e[8]=u2.x; e[9]=u2.y; e[10]=u2.z; e[11]=u2.w;
    e[12]=u3.x; e[13]=u3.y; e[14]=u3.z; e[15]=u3.w;
  }
  float mx = e[0];
  #pragma unroll
  for (int i = 1; i < 16; ++i) mx = fmaxf(mx, e[i]);
  mx = wredmax(mx);
  float s = 0.f;
  #pragma unroll
  for (int i = 0; i < 16; ++i) { e[i] = __expf(e[i]-mx); s += e[i]; }
  s = wredsum(s);
  float inv = 1.f/s;
  #pragma unroll
  for (int i = 0; i < 16; ++i) e[i] *= inv;

  uint32_t b4[4] = {0u, 0u, 0u, 0u};
  if (!zmode) {
    #pragma unroll
    for (int i = 0; i < 16; ++i)
      b4[i>>2] |= enc_e4m3(e[i]*WSCALE) << ((i&3)*8);
  } else {
    float s1[8], s2[4], s3[2], s4v;
    #pragma unroll
    for (int i = 0; i < 8; ++i) s1[i] = e[2*i] + e[2*i+1];
    #pragma unroll
    for (int i = 0; i < 4; ++i) s2[i] = s1[2*i] + s1[2*i+1];
    s3[0] = s2[0]+s2[1]; s3[1] = s2[2]+s2[3];
    s4v = s3[0]+s3[1];
    float s5 = s4v + __shfl_xor(s4v, 1, 64);
    float s6 = s5  + __shfl_xor(s5, 2, 64);
    float s7 = s6  + __shfl_xor(s6, 4, 64);
    float s8 = s7  + __shfl_xor(s7, 8, 64);
    float s9 = s8  + __shfl_xor(s8, 16, 64);
    const float* pk = consts + 8 + layer*(KKC+1);
    const float base = pk[4]*s4v + pk[5]*s5 + pk[6]*s6 + pk[7]*s7 + pk[8]*s8 + pk[9]*s9;
    const float p1 = pk[1], p2 = pk[2], p3 = pk[3], p10 = pk[10];
    #pragma unroll
    for (int i = 0; i < 16; ++i) {
      float v = p10*e[i] + p1*s1[i>>1] + p2*s2[i>>2] + p3*s3[i>>3] + base;
      b4[i>>2] |= enc_e4m3(v*ZSCALE) << ((i&3)*8);
    }
  }
  uint64_t u0 = (uint64_t)b4[0] | ((uint64_t)b4[1] << 32);
  uint64_t u1 = (uint64_t)b4[2] | ((uint64_t)b4[3] << 32);
  *(uint64_t*)(drow + p0)      = u0;
  *(uint64_t*)(drow + p0 + 16) = u1;
}

// ---------------- 128x256 fp8 GEMM: 1 barrier/tile, 2 blocks/CU + fused epilogue ----------------
// 8 waves (2Mx4N), wave tile 64x64, acc[4][4] (64 AGPR). BK=64B; buf = A 8KB + B 16KB = 24KB;
// 2 bufs (48KB) + 64KB C-stage => 64KB dynamic LDS, 2 blocks/CU, 4 waves/SIMD.
// Per tile u: {vmcnt(0); s_barrier; 8x ds_read_b128; stage(u+1) [3 gloads]; 32 MFMA}.
// Safety: a wave reaching barrier(u) has consumed (hence retired) all its tile-(u-1)
// ds_reads (hw lgkmcnt before MFMA), so stage(u+1)->buf^1 after barrier(u) is WAR-safe;
// own vmcnt(0)+barrier publishes stage(u) block-wide before reads(u).
__global__ __launch_bounds__(512, 4) void gemm_fused(
    const uint8_t* __restrict__ Az8, size_t zls,
    const uint8_t* __restrict__ Bw8, size_t wls,
    const float* __restrict__ a_tab, const float* __restrict__ b_tab,
    const float* __restrict__ g_tab, const float* __restrict__ d_tab,
    const float* __restrict__ consts, int layer0,
    const uint32_t* __restrict__ eoff, const uint16_t* __restrict__ ebuf,
    float* __restrict__ out)
{
  extern __shared__ char lds[];                // 64KB: 2 x 24KB bufs; epilogue uses all
  const int t = threadIdx.x;
  const int w = t >> 6, l = t & 63;
  const int wm = w >> 2, wn = w & 3;
  const int fr = l & 15, fq = l >> 4;

  // T1: bijective XCD swizzle (1536 blocks % 8 == 0)
  const int nbx = gridDim.x, nby = gridDim.y;   // 32, 16
  int lid = blockIdx.x + nbx*(blockIdx.y + nby*blockIdx.z);
  const int nblk = nbx*nby*gridDim.z;
  const int cpx = nblk >> 3;
  int nid = (lid & 7)*cpx + (lid >> 3);
  const int bz = nid / (nbx*nby);
  const int rem = nid % (nbx*nby);
  const int bi = rem % nbx, bj = rem / nbx;

  const int i0 = bi*128, j0 = bj*256;
  const int layer = layer0 + bz;
  Az8 += (size_t)bz*zls + (size_t)i0*1024;
  Bw8 += (size_t)bz*wls + (size_t)j0*1024;

  f32x4 acc[4][4];
  f32x4 zero = {0.f, 0.f, 0.f, 0.f};
  #pragma unroll
  for (int m = 0; m < 4; ++m)
    #pragma unroll
    for (int nn = 0; nn < 4; ++nn) acc[m][nn] = zero;

  // stage-side involution (verified R10/R11): lane l covers dest slot s=l&7 of
  // line pair L=l>>3; source granule go = s^(L&7); s_off within a 16-row chunk.
  const int go = (l & 7) ^ (l >> 3);
  const size_t s_off = (size_t)((l >> 3)*2 + (go >> 2))*1024 + (size_t)(go & 3)*16;
  // read-side slot (same conflict-free b128 pattern as R11)
  const int slot = (((fr & 1) << 2) + fq) ^ (fr >> 1);
  const int abase = wm*4096 + (fr>>1)*128 + slot*16;          // + m*1024
  const int bbase = 8192 + wn*4096 + (fr>>1)*128 + slot*16;   // + nn*1024

  longx2 ar2[4], br2[4];

#define STG_A(tile) do { \
    char* _d = lds + ((tile)&1)*24576 + w*1024; \
    const uint8_t* _s = Az8 + (size_t)(w*16)*1024 + (size_t)(tile)*64 + s_off; \
    global_load_lds16(_s, _d); \
  } while (0)
#define STG_B(tile) do { \
    char* _d = lds + ((tile)&1)*24576 + 8192 + w*2048; \
    const uint8_t* _s = Bw8 + (size_t)(w*32)*1024 + (size_t)(tile)*64 + s_off; \
    global_load_lds16(_s, _d); \
    global_load_lds16(_s + (size_t)16*1024, _d + 1024); \
  } while (0)

  // prologue: stage tile 0 into buf0
  STG_A(0); STG_B(0);

  for (int u = 0; u < 16; ++u) {
    const int cb = (u & 1)*24576;
    asm volatile("s_waitcnt vmcnt(0)" ::: "memory");   // own stage(u) landed
    asm volatile("s_barrier" ::: "memory");            // stage(u) visible block-wide
    #pragma unroll
    for (int i = 0; i < 4; ++i)
      ar2[i] = *(const longx2*)(lds + cb + abase + i*1024);
    #pragma unroll
    for (int j = 0; j < 4; ++j)
      br2[j] = *(const longx2*)(lds + cb + bbase + j*1024);
    if (u < 15) { STG_A(u+1); STG_B(u+1); }
    __builtin_amdgcn_s_setprio(1);
    #pragma unroll
    for (int i = 0; i < 4; ++i)
      #pragma unroll
      for (int j = 0; j < 4; ++j) {
        acc[i][j] = __builtin_amdgcn_mfma_f32_16x16x32_fp8_fp8(
            ar2[i].x, br2[j].x, acc[i][j], 0, 0, 0);
        acc[i][j] = __builtin_amdgcn_mfma_f32_16x16x32_fp8_fp8(
            ar2[i].y, br2[j].y, acc[i][j], 0, 0, 0);
      }
    __builtin_amdgcn_s_setprio(0);
  }
#undef STG_A
#undef STG_B

  // ---- epilogue: C (128x256 bf16 = 64KB) into LDS; dense softplus-sum + binned sparse ----
  __syncthreads();                       // all waves done reading buf1 before overwrite
  const float cc = consts[layer];
  {
    // row = wm*64 + m*16 + fq*4 + r ; col = wn*64 + nn*16 + fr ; byte = row*512 + col*2
    char* cbase = lds + wm*32768 + fq*2048 + wn*128 + fr*2;
    #pragma unroll
    for (int m = 0; m < 4; ++m)
      #pragma unroll
      for (int nn = 0; nn < 4; ++nn)
        #pragma unroll
        for (int r = 0; r < 4; ++r)
          *(bf16_t*)(cbase + m*8192 + r*512 + nn*32) =
              (bf16_t)(acc[m][nn][r]*INVSCALE + cc);
  }
  __syncthreads();

  const float* at = a_tab + layer*N1;
  const float* bt = b_tab + layer*N2;
  const float* gt = g_tab + layer*N1;
  const float* dt = d_tab + layer*N2;
  float dsum = 0.f;
  #pragma unroll 4
  for (int i = 0; i < 8; ++i) {
    const int id = t + i*512;            // 4096 chunks of 16B
    const int row = id >> 5, g = id & 31;
    bf16x8 v = *(const bf16x8*)(lds + row*512 + g*16);
    const int grow = i0 + row, gcol = j0 + g*8;
    const float av = at[grow], gv = gt[grow];
    float4 b0 = *(const float4*)(bt + gcol), b1 = *(const float4*)(bt + gcol + 4);
    float4 d0 = *(const float4*)(dt + gcol), d1 = *(const float4*)(dt + gcol + 4);
    float bb[8] = {b0.x,b0.y,b0.z,b0.w,b1.x,b1.y,b1.z,b1.w};
    float dd[8] = {d0.x,d0.y,d0.z,d0.w,d1.x,d1.y,d1.z,d1.w};
    #pragma unroll
    for (int e2 = 0; e2 < 8; ++e2) {
      float x = av*bb[e2]*(float)v[e2] + gv + dd[e2];
      float sp = softplus_fast(x);
      dsum += (grow != gcol + e2) ? sp : 0.f;
    }
  }
  const int bin = bz*NBIN_L + bi*16 + bj;
  const uint32_t e0 = eoff[bin], e1 = eoff[bin+1];
  float ssum = 0.f;
  for (uint32_t e = e0 + (uint32_t)t; e < e1; e += 512u) {
    const int pk2 = ebuf[e];
    const int li = pk2 >> 8, lj = pk2 & 255;
    float dc = (float)*(const bf16_t*)(lds + li*512 + lj*2);
    ssum += at[i0+li]*bt[j0+lj]*dc + gt[i0+li] + dt[j0+lj];
  }
  float tot = wredsum(ssum - dsum);
  __syncthreads();
  if (l == 0) ((float*)lds)[w] = tot;
  __syncthreads();
  if (t == 0) {
    const float* r = (const float*)lds;
    float s = 0.f;
    #pragma unroll
    for (int i = 0; i < 8; ++i) s += r[i];
    atomicAdd(out, s);   // ll += z_pdist2 - z_pdist1
  }
}

extern "C" void kernel_launch(void* const* d_in, const int* in_sizes, int n_in,
                              void* d_out, int out_size, void* d_ws, size_t ws_size,
                              hipStream_t stream) {
  const float* us    = (const float*)d_in[0];
  const float* vs    = (const float*)d_in[1];
  const float* gamma = (const float*)d_in[2];
  const float* delta = (const float*)d_in[3];
  const float* lz    = (const float*)d_in[4];
  const float* lw    = (const float*)d_in[5];
  const float* pks   = (const float*)d_in[6];
  const float* Lp    = (const float*)d_in[7];
  const int*   sis   = (const int*)d_in[8];
  const int*   sjs   = (const int*)d_in[9];
  float* out = (float*)d_out;
  char*  ws  = (char*)d_ws;
  const int E = in_sizes[8] / NLAYERS;

  size_t p = 0;
  float* consts = (float*)(ws + p); p += 1024;
  float* a_tab  = (float*)(ws + p); p += (size_t)NLAYERS*N1*4;
  float* b_tab  = (float*)(ws + p); p += (size_t)NLAYERS*N2*4;
  float* g_tab  = (float*)(ws + p); p += (size_t)NLAYERS*N1*4;
  float* d_tab  = (float*)(ws + p); p += (size_t)NLAYERS*N2*4;
  uint32_t* hist   = (uint32_t*)(ws + p); p += 2048*4;
  uint32_t* eoff   = (uint32_t*)(ws + p); p += 2048*4;
  uint32_t* cursor = (uint32_t*)(ws + p); p += 2048*4;
  uint16_t* ebuf   = (uint16_t*)(ws + p); p += (size_t)NLAYERS*E*2;
  p = (p + 4095) & ~(size_t)4095;
  uint8_t* zt8 = (uint8_t*)(ws + p); p += (size_t)NLAYERS*N1*1024;
  uint8_t* wt8 = (uint8_t*)(ws + p); p += (size_t)NLAYERS*N2*1024;
  if (ws_size < p) return;
  const size_t ZLS = (size_t)N1*1024;
  const size_t LDSB = 65536;
  const int nebl = (E + EPB - 1) / EPB;

  prep_small<<<(N1+255)/256, 256, 0, stream>>>(lz, lw, gamma, delta, pks, Lp,
                                               consts, a_tab, b_tab, g_tab, d_tab,
                                               hist, out);
  edge_hist<<<dim3(nebl, NLAYERS), 256, 0, stream>>>(sis, sjs, hist, E);
  edge_scan<<<1, 256, 0, stream>>>(hist, eoff, cursor);
  edge_scatter<<<dim3(nebl, NLAYERS), 256, 0, stream>>>(sis, sjs, cursor, ebuf, E);
  prep_rows<<<dim3(N1/4, NLAYERS, 2), 256, 0, stream>>>(us, vs, zt8, wt8, ZLS, consts, 0);
  gemm_fused<<<dim3(32,16,NLAYERS), 512, LDSB, stream>>>(
      zt8, ZLS, wt8, ZLS, a_tab, b_tab, g_tab, d_tab, consts, 0, eoff, ebuf, out);
}

// Round 13
// 139.305 us; speedup vs baseline: 4.1847x; 1.0042x over previous
//
#include <hip/hip_runtime.h>
#include <hip/hip_bf16.h>
#include <stdint.h>

#define EPSV 1e-6f
#define N1 4096
#define N2 4096
#define DD 1024
#define NLAYERS 3
#define KKC 10

typedef __bf16 bf16_t;
typedef __bf16 bf16x8 __attribute__((ext_vector_type(8)));
typedef float f32x4 __attribute__((ext_vector_type(4)));
typedef long longx2 __attribute__((ext_vector_type(2)));

#define ZSCALE 256.0f
#define WSCALE 64.0f
#define INVSCALE 6.103515625e-05f   // 1/(ZSCALE*WSCALE)

// bins: 32 i-bins (128 rows) x 16 j-bins (256 cols) = 512 per layer, 1536 total
#define NBIN_L 512
#define NBIN_T (NLAYERS*NBIN_L)

__device__ __forceinline__ float softplus_fast(float x) {
  return fmaxf(x, 0.f) + __logf(1.f + __expf(-fabsf(x)));
}
__device__ __forceinline__ float softplus_ref(float x) {
  return fmaxf(x, 0.f) + log1pf(expf(-fabsf(x)));
}
__device__ __forceinline__ float wredsum(float x) {
  #pragma unroll
  for (int o = 32; o; o >>= 1) x += __shfl_xor(x, o, 64);
  return x;
}
__device__ __forceinline__ float wredmax(float x) {
  #pragma unroll
  for (int o = 32; o; o >>= 1) x = fmaxf(x, __shfl_xor(x, o, 64));
  return x;
}
__device__ __forceinline__ void global_load_lds16(const void* g, void* l) {
  __builtin_amdgcn_global_load_lds(
      (const __attribute__((address_space(1))) uint32_t*)g,
      (__attribute__((address_space(3))) uint32_t*)l, 16, 0, 0);
}

// OCP e4m3fn encode, x in [0, 448], RNE. Denormal path: value = k*2^-9.
__device__ __forceinline__ uint32_t enc_e4m3(float x) {
  if (x < 0.015625f) return (uint32_t)__float2int_rn(x * 512.0f);
  uint32_t u = __float_as_uint(x);
  u += 0x7FFFFu + ((u >> 20) & 1u);
  return (((u >> 23) - 120u) << 3) | ((u >> 20) & 7u);
}

// ---------------- prep_small ----------------
__global__ __launch_bounds__(256) void prep_small(
    const float* __restrict__ lz, const float* __restrict__ lw,
    const float* __restrict__ gamma, const float* __restrict__ delta,
    const float* __restrict__ pks, const float* __restrict__ Lp,
    float* __restrict__ consts, float* __restrict__ a_tab, float* __restrict__ b_tab,
    float* __restrict__ g_tab, float* __restrict__ d_tab,
    uint32_t* __restrict__ hist, float* __restrict__ out)
{
  int n = blockIdx.x * blockDim.x + threadIdx.x;
  float Lv = softplus_ref(Lp[0]);
  if (n == 0) out[0] = 0.f;
  if (n < NBIN_T) hist[n] = 0u;
  if (n < N1) {
    float z0 = lz[n*3], z1 = lz[n*3+1], z2 = lz[n*3+2];
    float m = fmaxf(z0, fmaxf(z1, z2));
    float e0 = expf(z0-m), e1 = expf(z1-m), e2 = expf(z2-m);
    float inv = 1.f/(e0+e1+e2);
    a_tab[0*N1+n] = e0*inv*Lv; a_tab[1*N1+n] = e1*inv*Lv; a_tab[2*N1+n] = e2*inv*Lv;
    float w0 = lw[n*3], w1 = lw[n*3+1], w2 = lw[n*3+2];
    m = fmaxf(w0, fmaxf(w1, w2));
    e0 = expf(w0-m); e1 = expf(w1-m); e2 = expf(w2-m);
    inv = 1.f/(e0+e1+e2);
    b_tab[0*N2+n] = e0*inv+EPSV; b_tab[1*N2+n] = e1*inv+EPSV; b_tab[2*N2+n] = e2*inv+EPSV;
    #pragma unroll
    for (int k = 0; k < 3; ++k) {
      g_tab[k*N1+n] = gamma[n*3+k];
      d_tab[k*N2+n] = delta[n*3+k];
    }
  }
  if (n < NLAYERS) {
    float p[KKC+1]; float m = -1e30f;
    for (int k = 0; k <= KKC; ++k) { p[k] = pks[n*(KKC+1)+k]; m = fmaxf(m, p[k]); }
    float s = 0.f;
    for (int k = 0; k <= KKC; ++k) { p[k] = expf(p[k]-m); s += p[k]; }
    float inv = 1.f/s;
    for (int k = 0; k <= KKC; ++k) consts[8 + n*(KKC+1) + k] = p[k]*inv;
    consts[n] = p[0]*inv + EPSV*(1.f - p[0]*inv);
  }
}

// ---------------- edge binning ----------------
#define EPB 2048

__global__ __launch_bounds__(256) void edge_hist(
    const int* __restrict__ is_, const int* __restrict__ js_,
    uint32_t* __restrict__ hist, int E)
{
  __shared__ uint32_t h[NBIN_L];
  const int lay = blockIdx.y;
  const int t = threadIdx.x;
  h[t] = 0u; h[t+256] = 0u;
  __syncthreads();
  const int e0 = blockIdx.x * EPB;
  const int e1 = min(e0 + EPB, E);
  for (int e = e0 + t; e < e1; e += 256) {
    int i = is_[(size_t)lay*E + e], j = js_[(size_t)lay*E + e];
    atomicAdd(&h[(i>>7)*16 + (j>>8)], 1u);
  }
  __syncthreads();
  if (h[t])     atomicAdd(&hist[lay*NBIN_L + t], h[t]);
  if (h[t+256]) atomicAdd(&hist[lay*NBIN_L + t + 256], h[t+256]);
}

__global__ __launch_bounds__(256) void edge_scan(
    const uint32_t* __restrict__ hist, uint32_t* __restrict__ off,
    uint32_t* __restrict__ cursor)
{
  __shared__ uint32_t sa[NBIN_T], sb[NBIN_T];
  const int t = threadIdx.x;
  for (int i = t; i < NBIN_T; i += 256) sa[i] = hist[i];
  __syncthreads();
  uint32_t* src = sa; uint32_t* dst = sb;
  for (int s = 1; s < NBIN_T; s <<= 1) {
    for (int i = t; i < NBIN_T; i += 256) dst[i] = src[i] + (i >= s ? src[i-s] : 0u);
    __syncthreads();
    uint32_t* tmp = src; src = dst; dst = tmp;
  }
  for (int i = t; i < NBIN_T; i += 256) {
    uint32_t ex = i ? src[i-1] : 0u;
    off[i] = ex; cursor[i] = ex;
  }
  if (t == 0) off[NBIN_T] = src[NBIN_T-1];
}

__global__ __launch_bounds__(256) void edge_scatter(
    const int* __restrict__ is_, const int* __restrict__ js_,
    uint32_t* __restrict__ cursor, uint16_t* __restrict__ ebuf, int E)
{
  __shared__ uint32_t h[NBIN_L];
  __shared__ uint32_t basev[NBIN_L];
  const int lay = blockIdx.y;
  const int t = threadIdx.x;
  h[t] = 0u; h[t+256] = 0u;
  __syncthreads();
  const int e0 = blockIdx.x * EPB;
  const int e1 = min(e0 + EPB, E);
  for (int e = e0 + t; e < e1; e += 256) {
    int i = is_[(size_t)lay*E + e], j = js_[(size_t)lay*E + e];
    atomicAdd(&h[(i>>7)*16 + (j>>8)], 1u);
  }
  __syncthreads();
  basev[t]     = h[t]     ? atomicAdd(&cursor[lay*NBIN_L + t], h[t]) : 0u;
  basev[t+256] = h[t+256] ? atomicAdd(&cursor[lay*NBIN_L + t + 256], h[t+256]) : 0u;
  h[t] = 0u; h[t+256] = 0u;
  __syncthreads();
  for (int e = e0 + t; e < e1; e += 256) {
    int i = is_[(size_t)lay*E + e], j = js_[(size_t)lay*E + e];
    int b = (i>>7)*16 + (j>>8);
    uint32_t r = atomicAdd(&h[b], 1u);
    ebuf[basev[b] + r] = (uint16_t)(((i & 127) << 8) | (j & 255));
  }
}

// ---------------- prep_rows: wave-per-row softmax (+pyramid), fp8 PERMUTED output ----------------
__global__ __launch_bounds__(256) void prep_rows(
    const float* __restrict__ us, const float* __restrict__ vs,
    uint8_t* __restrict__ zt8, uint8_t* __restrict__ wt8, size_t lstride,
    const float* __restrict__ consts, int layer0)
{
  const int t = threadIdx.x, w = t >> 6, l = t & 63;
  const int n = blockIdx.x*4 + w;
  const int layer = layer0 + blockIdx.y;
  const int zmode = (blockIdx.z == 0);
  const float* src = (zmode ? us : vs) + ((size_t)layer*N1 + n)*DD + l*16;
  uint8_t* drow = (zmode ? zt8 : wt8) + (size_t)blockIdx.y*lstride + (size_t)n*1024;
  const int p0 = (l>>2)*64 + ((l&1)*2)*16 + ((l&3)>>1)*8;

  float e[16];
  {
    const float4* s4 = (const float4*)src;
    float4 u0 = s4[0], u1 = s4[1], u2 = s4[2], u3 = s4[3];
    e[0]=u0.x; e[1]=u0.y; e[2]=u0.z; e[3]=u0.w;
    e[4]=u1.x; e[5]=u1.y; e[6]=u1.z; e[7]=u1.w;
    e[8]=u2.x; e[9]=u2.y; e[10]=u2.z; e[11]=u2.w;
    e[12]=u3.x; e[13]=u3.y; e[14]=u3.z; e[15]=u3.w;
  }
  float mx = e[0];
  #pragma unroll
  for (int i = 1; i < 16; ++i) mx = fmaxf(mx, e[i]);
  mx = wredmax(mx);
  float s = 0.f;
  #pragma unroll
  for (int i = 0; i < 16; ++i) { e[i] = __expf(e[i]-mx); s += e[i]; }
  s = wredsum(s);
  float inv = 1.f/s;
  #pragma unroll
  for (int i = 0; i < 16; ++i) e[i] *= inv;

  uint32_t b4[4] = {0u, 0u, 0u, 0u};
  if (!zmode) {
    #pragma unroll
    for (int i = 0; i < 16; ++i)
      b4[i>>2] |= enc_e4m3(e[i]*WSCALE) << ((i&3)*8);
  } else {
    float s1[8], s2[4], s3[2], s4v;
    #pragma unroll
    for (int i = 0; i < 8; ++i) s1[i] = e[2*i] + e[2*i+1];
    #pragma unroll
    for (int i = 0; i < 4; ++i) s2[i] = s1[2*i] + s1[2*i+1];
    s3[0] = s2[0]+s2[1]; s3[1] = s2[2]+s2[3];
    s4v = s3[0]+s3[1];
    float s5 = s4v + __shfl_xor(s4v, 1, 64);
    float s6 = s5  + __shfl_xor(s5, 2, 64);
    float s7 = s6  + __shfl_xor(s6, 4, 64);
    float s8 = s7  + __shfl_xor(s7, 8, 64);
    float s9 = s8  + __shfl_xor(s8, 16, 64);
    const float* pk = consts + 8 + layer*(KKC+1);
    const float base = pk[4]*s4v + pk[5]*s5 + pk[6]*s6 + pk[7]*s7 + pk[8]*s8 + pk[9]*s9;
    const float p1 = pk[1], p2 = pk[2], p3 = pk[3], p10 = pk[10];
    #pragma unroll
    for (int i = 0; i < 16; ++i) {
      float v = p10*e[i] + p1*s1[i>>1] + p2*s2[i>>2] + p3*s3[i>>3] + base;
      b4[i>>2] |= enc_e4m3(v*ZSCALE) << ((i&3)*8);
    }
  }
  uint64_t u0 = (uint64_t)b4[0] | ((uint64_t)b4[1] << 32);
  uint64_t u1 = (uint64_t)b4[2] | ((uint64_t)b4[3] << 32);
  *(uint64_t*)(drow + p0)      = u0;
  *(uint64_t*)(drow + p0 + 16) = u1;
}

// ---------------- 128x256 fp8 GEMM: 1 barrier/tile, 2 blocks/CU + fused epilogue ----------------
// 8 waves (2Mx4N), wave tile 64x64, acc[4][4] (64 AGPR). BK=64B; buf = A 8KB + B 16KB = 24KB;
// 2 bufs (48KB) + 64KB C-stage => 64KB dynamic LDS, 2 blocks/CU, 4 waves/SIMD.
// Per tile u: {vmcnt(0); s_barrier; 8x ds_read_b128; stage(u+1) [3 gloads]; 32 MFMA}.
// Safety: a wave reaching barrier(u) has consumed (hence retired) all its tile-(u-1)
// ds_reads (hw lgkmcnt before MFMA), so stage(u+1)->buf^1 after barrier(u) is WAR-safe;
// own vmcnt(0)+barrier publishes stage(u) block-wide before reads(u).
__global__ __launch_bounds__(512, 4) void gemm_fused(
    const uint8_t* __restrict__ Az8, size_t zls,
    const uint8_t* __restrict__ Bw8, size_t wls,
    const float* __restrict__ a_tab, const float* __restrict__ b_tab,
    const float* __restrict__ g_tab, const float* __restrict__ d_tab,
    const float* __restrict__ consts, int layer0,
    const uint32_t* __restrict__ eoff, const uint16_t* __restrict__ ebuf,
    float* __restrict__ out)
{
  extern __shared__ char lds[];                // 64KB: 2 x 24KB bufs; epilogue uses all
  const int t = threadIdx.x;
  const int w = t >> 6, l = t & 63;
  const int wm = w >> 2, wn = w & 3;
  const int fr = l & 15, fq = l >> 4;

  // T1: bijective XCD swizzle (1536 blocks % 8 == 0)
  const int nbx = gridDim.x, nby = gridDim.y;   // 32, 16
  int lid = blockIdx.x + nbx*(blockIdx.y + nby*blockIdx.z);
  const int nblk = nbx*nby*gridDim.z;
  const int cpx = nblk >> 3;
  int nid = (lid & 7)*cpx + (lid >> 3);
  const int bz = nid / (nbx*nby);
  const int rem = nid % (nbx*nby);
  const int bi = rem % nbx, bj = rem / nbx;

  const int i0 = bi*128, j0 = bj*256;
  const int layer = layer0 + bz;
  Az8 += (size_t)bz*zls + (size_t)i0*1024;
  Bw8 += (size_t)bz*wls + (size_t)j0*1024;

  f32x4 acc[4][4];
  f32x4 zero = {0.f, 0.f, 0.f, 0.f};
  #pragma unroll
  for (int m = 0; m < 4; ++m)
    #pragma unroll
    for (int nn = 0; nn < 4; ++nn) acc[m][nn] = zero;

  // stage-side involution (verified R10/R11): lane l covers dest slot s=l&7 of
  // line pair L=l>>3; source granule go = s^(L&7); s_off within a 16-row chunk.
  const int go = (l & 7) ^ (l >> 3);
  const size_t s_off = (size_t)((l >> 3)*2 + (go >> 2))*1024 + (size_t)(go & 3)*16;
  // read-side slot (same conflict-free b128 pattern as R11)
  const int slot = (((fr & 1) << 2) + fq) ^ (fr >> 1);
  const int abase = wm*4096 + (fr>>1)*128 + slot*16;          // + m*1024
  const int bbase = 8192 + wn*4096 + (fr>>1)*128 + slot*16;   // + nn*1024

  longx2 ar2[4], br2[4];

#define STG_A(tile) do { \
    char* _d = lds + ((tile)&1)*24576 + w*1024; \
    const uint8_t* _s = Az8 + (size_t)(w*16)*1024 + (size_t)(tile)*64 + s_off; \
    global_load_lds16(_s, _d); \
  } while (0)
#define STG_B(tile) do { \
    char* _d = lds + ((tile)&1)*24576 + 8192 + w*2048; \
    const uint8_t* _s = Bw8 + (size_t)(w*32)*1024 + (size_t)(tile)*64 + s_off; \
    global_load_lds16(_s, _d); \
    global_load_lds16(_s + (size_t)16*1024, _d + 1024); \
  } while (0)

  // prologue: stage tile 0 into buf0
  STG_A(0); STG_B(0);

  for (int u = 0; u < 16; ++u) {
    const int cb = (u & 1)*24576;
    asm volatile("s_waitcnt vmcnt(0)" ::: "memory");   // own stage(u) landed
    asm volatile("s_barrier" ::: "memory");            // stage(u) visible block-wide
    #pragma unroll
    for (int i = 0; i < 4; ++i)
      ar2[i] = *(const longx2*)(lds + cb + abase + i*1024);
    #pragma unroll
    for (int j = 0; j < 4; ++j)
      br2[j] = *(const longx2*)(lds + cb + bbase + j*1024);
    if (u < 15) { STG_A(u+1); STG_B(u+1); }
    __builtin_amdgcn_s_setprio(1);
    #pragma unroll
    for (int i = 0; i < 4; ++i)
      #pragma unroll
      for (int j = 0; j < 4; ++j) {
        acc[i][j] = __builtin_amdgcn_mfma_f32_16x16x32_fp8_fp8(
            ar2[i].x, br2[j].x, acc[i][j], 0, 0, 0);
        acc[i][j] = __builtin_amdgcn_mfma_f32_16x16x32_fp8_fp8(
            ar2[i].y, br2[j].y, acc[i][j], 0, 0, 0);
      }
    __builtin_amdgcn_s_setprio(0);
  }
#undef STG_A
#undef STG_B

  // ---- epilogue: C (128x256 bf16 = 64KB) into LDS; dense softplus-sum + binned sparse ----
  __syncthreads();                       // all waves done reading buf1 before overwrite
  const float cc = consts[layer];
  {
    // row = wm*64 + m*16 + fq*4 + r ; col = wn*64 + nn*16 + fr ; byte = row*512 + col*2
    char* cbase = lds + wm*32768 + fq*2048 + wn*128 + fr*2;
    #pragma unroll
    for (int m = 0; m < 4; ++m)
      #pragma unroll
      for (int nn = 0; nn < 4; ++nn)
        #pragma unroll
        for (int r = 0; r < 4; ++r)
          *(bf16_t*)(cbase + m*8192 + r*512 + nn*32) =
              (bf16_t)(acc[m][nn][r]*INVSCALE + cc);
  }
  __syncthreads();

  const float* at = a_tab + layer*N1;
  const float* bt = b_tab + layer*N2;
  const float* gt = g_tab + layer*N1;
  const float* dt = d_tab + layer*N2;
  float dsum = 0.f;
  #pragma unroll 4
  for (int i = 0; i < 8; ++i) {
    const int id = t + i*512;            // 4096 chunks of 16B
    const int row = id >> 5, g = id & 31;
    bf16x8 v = *(const bf16x8*)(lds + row*512 + g*16);
    const int grow = i0 + row, gcol = j0 + g*8;
    const float av = at[grow], gv = gt[grow];
    float4 b0 = *(const float4*)(bt + gcol), b1 = *(const float4*)(bt + gcol + 4);
    float4 d0 = *(const float4*)(dt + gcol), d1 = *(const float4*)(dt + gcol + 4);
    float bb[8] = {b0.x,b0.y,b0.z,b0.w,b1.x,b1.y,b1.z,b1.w};
    float dd[8] = {d0.x,d0.y,d0.z,d0.w,d1.x,d1.y,d1.z,d1.w};
    #pragma unroll
    for (int e2 = 0; e2 < 8; ++e2) {
      float x = av*bb[e2]*(float)v[e2] + gv + dd[e2];
      float sp = softplus_fast(x);
      dsum += (grow != gcol + e2) ? sp : 0.f;
    }
  }
  const int bin = bz*NBIN_L + bi*16 + bj;
  const uint32_t e0 = eoff[bin], e1 = eoff[bin+1];
  float ssum = 0.f;
  for (uint32_t e = e0 + (uint32_t)t; e < e1; e += 512u) {
    const int pk2 = ebuf[e];
    const int li = pk2 >> 8, lj = pk2 & 255;
    float dc = (float)*(const bf16_t*)(lds + li*512 + lj*2);
    ssum += at[i0+li]*bt[j0+lj]*dc + gt[i0+li] + dt[j0+lj];
  }
  float tot = wredsum(ssum - dsum);
  __syncthreads();
  if (l == 0) ((float*)lds)[w] = tot;
  __syncthreads();
  if (t == 0) {
    const float* r = (const float*)lds;
    float s = 0.f;
    #pragma unroll
    for (int i = 0; i < 8; ++i) s += r[i];
    atomicAdd(out, s);   // ll += z_pdist2 - z_pdist1
  }
}

extern "C" void kernel_launch(void* const* d_in, const int* in_sizes, int n_in,
                              void* d_out, int out_size, void* d_ws, size_t ws_size,
                              hipStream_t stream) {
  const float* us    = (const float*)d_in[0];
  const float* vs    = (const float*)d_in[1];
  const float* gamma = (const float*)d_in[2];
  const float* delta = (const float*)d_in[3];
  const float* lz    = (const float*)d_in[4];
  const float* lw    = (const float*)d_in[5];
  const float* pks   = (const float*)d_in[6];
  const float* Lp    = (const float*)d_in[7];
  const int*   sis   = (const int*)d_in[8];
  const int*   sjs   = (const int*)d_in[9];
  float* out = (float*)d_out;
  char*  ws  = (char*)d_ws;
  const int E = in_sizes[8] / NLAYERS;

  size_t p = 0;
  float* consts = (float*)(ws + p); p += 1024;
  float* a_tab  = (float*)(ws + p); p += (size_t)NLAYERS*N1*4;
  float* b_tab  = (float*)(ws + p); p += (size_t)NLAYERS*N2*4;
  float* g_tab  = (float*)(ws + p); p += (size_t)NLAYERS*N1*4;
  float* d_tab  = (float*)(ws + p); p += (size_t)NLAYERS*N2*4;
  uint32_t* hist   = (uint32_t*)(ws + p); p += 2048*4;
  uint32_t* eoff   = (uint32_t*)(ws + p); p += 2048*4;
  uint32_t* cursor = (uint32_t*)(ws + p); p += 2048*4;
  uint16_t* ebuf   = (uint16_t*)(ws + p); p += (size_t)NLAYERS*E*2;
  p = (p + 4095) & ~(size_t)4095;
  uint8_t* zt8 = (uint8_t*)(ws + p); p += (size_t)NLAYERS*N1*1024;
  uint8_t* wt8 = (uint8_t*)(ws + p); p += (size_t)NLAYERS*N2*1024;
  if (ws_size < p) return;
  const size_t ZLS = (size_t)N1*1024;
  const size_t LDSB = 65536;
  const int nebl = (E + EPB - 1) / EPB;

  prep_small<<<(N1+255)/256, 256, 0, stream>>>(lz, lw, gamma, delta, pks, Lp,
                                               consts, a_tab, b_tab, g_tab, d_tab,
                                               hist, out);
  edge_hist<<<dim3(nebl, NLAYERS), 256, 0, stream>>>(sis, sjs, hist, E);
  edge_scan<<<1, 256, 0, stream>>>(hist, eoff, cursor);
  edge_scatter<<<dim3(nebl, NLAYERS), 256, 0, stream>>>(sis, sjs, cursor, ebuf, E);
  prep_rows<<<dim3(N1/4, NLAYERS, 2), 256, 0, stream>>>(us, vs, zt8, wt8, ZLS, consts, 0);
  gemm_fused<<<dim3(32,16,NLAYERS), 512, LDSB, stream>>>(
      zt8, ZLS, wt8, ZLS, a_tab, b_tab, g_tab, d_tab, consts, 0, eoff, ebuf, out);
}